// Round 10
// baseline (742.112 us; speedup 1.0000x reference)
//
#include <hip/hip_runtime.h>
#include <hip/hip_bf16.h>

typedef unsigned short u16;
typedef unsigned int u32;
typedef __attribute__((ext_vector_type(8))) short short8_t;   // 8 bf16 (4 VGPRs)
typedef __attribute__((ext_vector_type(4))) float f32x4;

// ---- static problem config ----
#define NSUBJ 8
#define TOTAL 6848
#define MPAD  6912          // 54 * 128
#define DM    768
#define DI    1536
#define DS    16
#define DTR   48
#define DXP   80            // DTR + 2*DS
#define EPSN  1e-5f
#define CH    64            // scan chunk length (R8 lesson: CH=32 overflows the
                            // Pb/Hin alias region: NCH*16*DI*4 must fit MPAD*768*2)
#define NCH   107           // TOTAL / CH

__constant__ int d_OFF[NSUBJ + 1] = {0, 1024, 1920, 2688, 3712, 4224, 4864, 5824, 6848};

struct BTrue  { static constexpr bool value = true;  };
struct BFalse { static constexpr bool value = false; };

// ---- helpers ----
__device__ __forceinline__ float b2f(u16 u) {
    return __uint_as_float(((u32)u) << 16);
}
__device__ __forceinline__ u16 f2b(float f) {
    u32 u = __float_as_uint(f);
    u32 r = (u + 0x7FFFu + ((u >> 16) & 1u)) >> 16;
    return (u16)r;
}
__device__ __forceinline__ float ldin(const void* p, size_t i, int f32f) {
    return f32f ? ((const float*)p)[i] : b2f(((const u16*)p)[i]);
}

__device__ __forceinline__ void unp8(uint4 v, float* o) {
    u32 a0 = v.x, a1 = v.y, a2 = v.z, a3 = v.w;
    o[0] = __uint_as_float(a0 << 16);  o[1] = __uint_as_float(a0 & 0xFFFF0000u);
    o[2] = __uint_as_float(a1 << 16);  o[3] = __uint_as_float(a1 & 0xFFFF0000u);
    o[4] = __uint_as_float(a2 << 16);  o[5] = __uint_as_float(a2 & 0xFFFF0000u);
    o[6] = __uint_as_float(a3 << 16);  o[7] = __uint_as_float(a3 & 0xFFFF0000u);
}

// async global -> LDS, 16B per lane; LDS dest must be wave-uniform base + lane*16
__device__ __forceinline__ void gld16(const u16* g, u16* l) {
    __builtin_amdgcn_global_load_lds(
        (const __attribute__((address_space(1))) void*)g,
        (__attribute__((address_space(3))) void*)l, 16, 0, 0);
}

__device__ __forceinline__ float block_sum(float v) {
    __shared__ float sbuf[8];
    __syncthreads();
    #pragma unroll
    for (int o = 32; o > 0; o >>= 1) v += __shfl_down(v, o, 64);
    const int lane = threadIdx.x & 63, w = threadIdx.x >> 6;
    if (lane == 0) sbuf[w] = v;
    __syncthreads();
    if (threadIdx.x == 0) sbuf[4] = sbuf[0] + sbuf[1] + sbuf[2] + sbuf[3];
    __syncthreads();
    return sbuf[4];
}

// ---- dtype detection ----
__global__ void detect_dtype(const u16* __restrict__ probe, int* __restrict__ flag) {
    const int lane = threadIdx.x;
    int cnt = 0;
    for (int i = 0; i < 32; ++i) {
        const u16 v = probe[lane * 32 + i];
        if (((v >> 7) & 0xFF) >= 0x90) cnt++;
    }
    #pragma unroll
    for (int o = 32; o > 0; o >>= 1) cnt += __shfl_down(cnt, o, 64);
    if (lane == 0) *flag = (cnt > 64) ? 1 : 0;
}

// ---- weight -> bf16 ws copy (convert if f32, plain copy if bf16) ----
__global__ void cvt_any(const void* __restrict__ src, u16* __restrict__ dst, int n,
                        const int* __restrict__ flagp) {
    const int f32f = *flagp;
    const int i = blockIdx.x * 256 + threadIdx.x;
    if (i < n) dst[i] = f32f ? f2b(((const float*)src)[i]) : ((const u16*)src)[i];
}

// ---- dt_proj weights repacked planar: dst[l][jb][c][8] bf16, jb = dt-rank chunk (48 = 6*8) ----
__global__ void cvt_dtp(const void* __restrict__ src, u16* __restrict__ dst,
                        const int* __restrict__ flagp) {
    const int f32f = *flagp;
    const int i = blockIdx.x * 256 + threadIdx.x;
    if (i >= 2 * 6 * DI * 8) return;
    const int j = i & 7;
    const int c = (i >> 3) % DI;
    const int jb = ((i >> 3) / DI) % 6;
    const int l = i / (8 * DI * 6);
    dst[i] = f2b(ldin(src, ((size_t)(l * DI + c)) * DTR + jb * 8 + j, f32f));
}

// ---- precompute: conv weights [l][tap][c] f32, conv bias f32, nA = -exp(A_log) [l][n][c] ----
__global__ void prep_conv(const void* __restrict__ cw, const void* __restrict__ cb,
                          const void* __restrict__ A_log,
                          float* __restrict__ cwT, float* __restrict__ cbF,
                          float* __restrict__ nA, const int* __restrict__ flagp) {
    const int f32f = *flagp;
    const int i = blockIdx.x * 256 + threadIdx.x;
    if (i < 2 * 4 * DI) {
        const int l = i / (4 * DI), r = i - l * 4 * DI;
        const int tap = r / DI, c = r - tap * DI;
        cwT[i] = ldin(cw, (size_t)l * DI * 4 + (size_t)c * 4 + tap, f32f);
    }
    if (i < 2 * DI) cbF[i] = ldin(cb, i, f32f);
    if (i < 2 * 16 * DI) {
        const int l = i / (16 * DI), r = i - l * 16 * DI;
        const int n = r / DI, c = r - n * DI;
        nA[i] = -__expf(ldin(A_log, (size_t)l * DI * DS + (size_t)c * DS + n, f32f));
    }
}

// ---- check A[n] = (n+1)*A[0] structure (Mamba default init) ----
__global__ void chk_A(const float* __restrict__ nA, int* __restrict__ flagA) {
    int viol = 0;
    for (int i = threadIdx.x; i < 2 * 16 * DI; i += 256) {
        const int l = i / (16 * DI);
        const int rem = i - l * 16 * DI;
        const int n = rem / DI;
        const int c = rem - n * DI;
        const float a1 = nA[l * 16 * DI + c];
        const float want = (float)(n + 1) * a1;
        const float got = nA[i];
        if (fabsf(got - want) > 1e-4f * fabsf(want) + 1e-6f) viol = 1;
    }
    const float v = block_sum((float)viol);
    if (threadIdx.x == 0) *flagA = (v == 0.f) ? 1 : 0;
}

// ---- fused: embedding gather + rmsnorm(in_norm) -> h f32 AND rmsnorm(norm_w[0]) -> bf16 normed ----
__global__ void embed_rms2(const int* __restrict__ tokens, const void* __restrict__ embed,
                           const void* __restrict__ w_in, const void* __restrict__ w_l0,
                           float* __restrict__ h, u16* __restrict__ normed,
                           const int* __restrict__ flagp) {
    const int f32f = *flagp;
    const int f = blockIdx.x;
    const int tid = threadIdx.x;
    const int row = tokens[f];
    float v[3]; float ss = 0.f;
    #pragma unroll
    for (int i = 0; i < 3; ++i) {
        v[i] = ldin(embed, (size_t)row * DM + tid + 256 * i, f32f);
        ss += v[i] * v[i];
    }
    float tot = block_sum(ss);
    float rs = rsqrtf(tot * (1.f / DM) + EPSN);
    float ss2 = 0.f;
    #pragma unroll
    for (int i = 0; i < 3; ++i) {
        v[i] = v[i] * rs * ldin(w_in, tid + 256 * i, f32f);
        h[(size_t)f * DM + tid + 256 * i] = v[i];
        ss2 += v[i] * v[i];
    }
    tot = block_sum(ss2);
    rs = rsqrtf(tot * (1.f / DM) + EPSN);
    #pragma unroll
    for (int i = 0; i < 3; ++i)
        normed[(size_t)f * DM + tid + 256 * i] =
            f2b(v[i] * rs * ldin(w_l0, tid + 256 * i, f32f));
}

// ---- MFMA GEMM: C[M,N] = A[M,K](lda) * B[N,K](ldb)^T, bf16 in, f32 acc ----
// R9 post-mortem: band swizzle cut FETCH 61->44MB but SLOWED the dispatch
// (not BW-bound) -> reverted to linear order. Counted-vmcnt: null (R7/m131)
// -> reverted to plain __syncthreads 2-phase.
// R10: TWO K-tiles per barrier interval (BK=64 effective). Each 32-wide
// sub-tile keeps the R7-proven staging map + XOR swizzle byte-identical;
// barrier count halves (24->12 for in_proj), 32 MFMA of cover per drain.
// REQUIRES: (ksplit/32) even at every call site (24 / 6 / 48: all even).
// EPI: 0 = store bf16; 3 = f32 partial Pbuf[z][M][N]
template <int EPI, int TN_>
__global__ __launch_bounds__(256)
void gemm_bt(const u16* __restrict__ A, const u16* __restrict__ B,
             void* __restrict__ Cv, float* __restrict__ Pbuf,
             const int* __restrict__ flagp,
             int M, int N, int K, int lda, int ldb, int ldc, int ksplit) {
    constexpr int NJ = TN_ / 32;
    __shared__ u16 sA[2][2][128 * 32];
    __shared__ u16 sB[2][2][TN_ * 32];
    const int tid = threadIdx.x;
    const int bm = blockIdx.x * 128;
    const int bn = blockIdx.y * TN_;
    const int lane = tid & 63, w = tid >> 6;
    const int wm = (w >> 1) * 64;
    const int wn = (w & 1) * (TN_ / 2);
    const int lr = lane & 15;
    const int q = lane >> 4;
    const int sw = (q ^ (lr & 3)) * 8;          // swizzled k-slot (u16 elems)

    int oA[4]; int oB[NJ];
    #pragma unroll
    for (int i = 0; i < 4; ++i) oA[i] = (wm + i * 16 + lr) * 32 + sw;
    #pragma unroll
    for (int j = 0; j < NJ; ++j) oB[j] = (wn + j * 16 + lr) * 32 + sw;

    const int r0 = tid >> 2;
    const int kp = ((tid & 3) ^ (r0 & 3)) * 8;  // global k offset (elems)

    const u16* gA0 = A + (size_t)(bm + r0) * lda + kp;
    const u16* gA1 = A + (size_t)(bm + r0 + 64) * lda + kp;
    const u16* gB0 = B + (size_t)(bn + r0) * ldb + kp;
    const u16* gB1 = (TN_ == 128) ? (B + (size_t)(bn + r0 + 64) * ldb + kp) : nullptr;

    f32x4 acc[4][NJ];
    #pragma unroll
    for (int i = 0; i < 4; ++i)
        #pragma unroll
        for (int j = 0; j < NJ; ++j)
            acc[i][j] = (f32x4){0.f, 0.f, 0.f, 0.f};

    const int kb = blockIdx.z * ksplit;
    const int ke = (kb + ksplit < K) ? (kb + ksplit) : K;
    const int nt = (ke - kb) >> 5;              // K tiles; EVEN at all call sites

    auto stage1 = [&](int b, int s, int t) {    // stage K-tile t into sub-buffer s
        const int k0 = kb + t * 32;
        gld16(gA0 + k0, &sA[b][s][tid * 8]);
        gld16(gA1 + k0, &sA[b][s][(256 + tid) * 8]);
        gld16(gB0 + k0, &sB[b][s][tid * 8]);
        if constexpr (TN_ == 128) gld16(gB1 + k0, &sB[b][s][(256 + tid) * 8]);
    };

    // prologue: stage first pair; barrier drains vmcnt(0)
    stage1(0, 0, 0);
    stage1(0, 1, 1);
    __syncthreads();

    int cur = 0;
    for (int t = 0; t < nt; t += 2) {
        if (t + 2 < nt) {                       // prefetch next pair FIRST
            stage1(cur ^ 1, 0, t + 2);
            stage1(cur ^ 1, 1, t + 3);
        }

        #pragma unroll
        for (int s = 0; s < 2; ++s) {
            short8_t af[4], bfr[NJ];
            #pragma unroll
            for (int i = 0; i < 4; ++i) af[i] = *(const short8_t*)&sA[cur][s][oA[i]];
            #pragma unroll
            for (int j = 0; j < NJ; ++j) bfr[j] = *(const short8_t*)&sB[cur][s][oB[j]];
            #pragma unroll
            for (int i = 0; i < 4; ++i)
                #pragma unroll
                for (int j = 0; j < NJ; ++j)
                    acc[i][j] = __builtin_amdgcn_mfma_f32_16x16x32_bf16(af[i], bfr[j], acc[i][j], 0, 0, 0);
        }

        __syncthreads();   // drains vmcnt(0): prefetched pair now resident
        cur ^= 1;
    }

    // epilogue: C/D layout col=lane&15, row=(lane>>4)*4 + reg   [verified m89/m91]
    const int cr = (lane >> 4) * 4;
    const int cc = lane & 15;
    #pragma unroll
    for (int i = 0; i < 4; ++i) {
        const int gm0 = bm + wm + i * 16 + cr;
        #pragma unroll
        for (int j = 0; j < NJ; ++j) {
            const int gn = bn + wn + j * 16 + cc;
            if (gn < N) {
                #pragma unroll
                for (int r = 0; r < 4; ++r) {
                    float v = acc[i][j][r];
                    const size_t idx = (size_t)(gm0 + r) * ldc + gn;
                    if (EPI == 0) {
                        ((u16*)Cv)[idx] = f2b(v);
                    } else {
                        Pbuf[(size_t)blockIdx.z * M * N + idx] = v;
                    }
                }
            }
        }
    }
}

// ---- fused: reduce 8 x_proj split-K partials -> bf16 dbl [MPAD,80]
//      AND dt_proj(rank-48) + softplus -> dtb [MPAD,1536].
__global__ __launch_bounds__(256)
void reduce_xp_dt(u16* __restrict__ dbl, u16* __restrict__ dtb,
                  const float* __restrict__ P, const u16* __restrict__ wdt,
                  const void* __restrict__ bias, int bias_off,
                  const int* __restrict__ flagp) {
    __shared__ float sdt[8 * DTR];              // [tok][48] f32
    const int f32f = *flagp;
    const int tid = threadIdx.x;
    const int g0 = blockIdx.x * 8;              // first token row of this block

    #pragma unroll
    for (int it = 0; it < 3; ++it) {
        const int idx = tid + it * 256;
        if (idx < 8 * DXP) {
            const size_t base = (size_t)g0 * DXP + idx;
            float s = 0.f;
            #pragma unroll
            for (int z = 0; z < 8; ++z) s += P[(size_t)z * MPAD * DXP + base];
            dbl[base] = f2b(s);
            const int tok = idx / DXP, col = idx - tok * DXP;
            if (col < DTR) sdt[tok * DTR + col] = s;
        }
    }
    __syncthreads();

    #pragma unroll 1
    for (int p = 0; p < 2; ++p) {
        float acc[3][8];
        #pragma unroll
        for (int kc = 0; kc < 3; ++kc)
            #pragma unroll
            for (int t = 0; t < 8; ++t) acc[kc][t] = 0.f;

        #pragma unroll 1
        for (int jb = 0; jb < 6; ++jb) {        // 6 chunks of 8 dt-rank dims
            float w[3][8];
            #pragma unroll
            for (int kc = 0; kc < 3; ++kc) {
                const int c = tid + (p * 3 + kc) * 256;
                const uint4 wv = *(const uint4*)(wdt + ((size_t)jb * DI + c) * 8);
                unp8(wv, w[kc]);
            }
            #pragma unroll
            for (int t = 0; t < 8; ++t) {
                float sj[8];
                *(float4*)&sj[0] = *(const float4*)&sdt[t * DTR + jb * 8];
                *(float4*)&sj[4] = *(const float4*)&sdt[t * DTR + jb * 8 + 4];
                #pragma unroll
                for (int kc = 0; kc < 3; ++kc)
                    #pragma unroll
                    for (int j = 0; j < 8; ++j)
                        acc[kc][t] += w[kc][j] * sj[j];
            }
        }

        #pragma unroll
        for (int kc = 0; kc < 3; ++kc) {
            const int c = tid + (p * 3 + kc) * 256;
            const float bv = ldin(bias, (size_t)(bias_off + c), f32f);
            #pragma unroll
            for (int t = 0; t < 8; ++t) {
                float v = acc[kc][t] + bv;
                v = (v > 20.f) ? v : __logf(1.f + __expf(v));
                dtb[(size_t)(g0 + t) * DI + c] = f2b(v);
            }
        }
    }
}

// ---- fused: h += out_proj partial (single slab) AND rmsnorm -> bf16 normed ----
__global__ void reduce_out_rms(float* __restrict__ h, const float* __restrict__ P,
                               const void* __restrict__ w, int woff,
                               u16* __restrict__ out, const int* __restrict__ flagp) {
    const int f32f = *flagp;
    const int f = blockIdx.x;
    const int tid = threadIdx.x;
    float v[3]; float ss = 0.f;
    #pragma unroll
    for (int i = 0; i < 3; ++i) {
        const size_t idx = (size_t)f * DM + tid + 256 * i;
        const float a = h[idx] + P[idx];
        h[idx] = a; v[i] = a; ss += a * a;
    }
    const float tot = block_sum(ss);
    const float rs = rsqrtf(tot * (1.f / DM) + EPSN);
    #pragma unroll
    for (int i = 0; i < 3; ++i)
        out[(size_t)f * DM + tid + 256 * i] =
            f2b(v[i] * rs * ldin(w, woff + tid + 256 * i, f32f));
}

// ---- fused: h += partial AND double rmsnorm -> d_out (end fusion) ----
__global__ void reduce_out_final(const float* __restrict__ h, const float* __restrict__ P,
                                 const void* __restrict__ wf, const void* __restrict__ wo,
                                 void* __restrict__ out, const int* __restrict__ flagp) {
    const int f32f = *flagp;
    const int f = blockIdx.x;
    const int tid = threadIdx.x;
    float v[3]; float ss = 0.f;
    #pragma unroll
    for (int i = 0; i < 3; ++i) {
        const size_t idx = (size_t)f * DM + tid + 256 * i;
        v[i] = h[idx] + P[idx];
        ss += v[i] * v[i];
    }
    float tot = block_sum(ss);
    float rs = rsqrtf(tot * (1.f / DM) + EPSN);
    float ss2 = 0.f;
    #pragma unroll
    for (int i = 0; i < 3; ++i) {
        v[i] = v[i] * rs * ldin(wf, tid + 256 * i, f32f);
        ss2 += v[i] * v[i];
    }
    tot = block_sum(ss2);
    rs = rsqrtf(tot * (1.f / DM) + EPSN);
    #pragma unroll
    for (int i = 0; i < 3; ++i) {
        const float r = v[i] * rs * ldin(wo, tid + 256 * i, f32f);
        const size_t idx = (size_t)f * DM + tid + 256 * i;
        if (f32f) ((float*)out)[idx] = r;
        else      ((u16*)out)[idx] = f2b(r);
    }
}

// ---- causal depthwise conv(K=4) + bias + silu; fully coalesced ----
__global__ void conv_silu(const u16* __restrict__ xz, const float* __restrict__ cwT,
                          const float* __restrict__ cbF, u16* __restrict__ xc) {
    const int gid = blockIdx.x * 256 + threadIdx.x;
    if (gid >= TOTAL * (DI / 2)) return;
    const int f = gid / (DI / 2);
    const int c = (gid - f * (DI / 2)) * 2;
    int s = 0;
    while (f >= d_OFF[s + 1]) s++;
    const int t = f - d_OFF[s];

    float2 acc = *(const float2*)(cbF + c);
    #pragma unroll
    for (int j = 0; j < 4; ++j) {
        if (t - 3 + j >= 0) {
            const u32 xp = *(const u32*)(xz + (size_t)(f - 3 + j) * (2 * DI) + c);
            const float2 wv = *(const float2*)(cwT + j * DI + c);
            acc.x += __uint_as_float(xp << 16) * wv.x;
            acc.y += __uint_as_float(xp & 0xFFFF0000u) * wv.y;
        }
    }
    const float s0 = acc.x / (1.f + __expf(-acc.x));
    const float s1 = acc.y / (1.f + __expf(-acc.y));
    *(u32*)(xc + (size_t)f * DI + c) = (u32)f2b(s0) | ((u32)f2b(s1) << 16);
}

// ==================== chunk-parallel selective scan (3 passes) ====================
__global__ __launch_bounds__(256)
void scan_part1(const u16* __restrict__ xcb, const u16* __restrict__ dtb,
                const u16* __restrict__ dbl,
                const float* __restrict__ nA, int aoff,
                float* __restrict__ Pb, float* __restrict__ Sb,
                const int* __restrict__ flagA) {
    __shared__ float sB[CH * 16];
    const int ch = blockIdx.x;
    const int g0 = ch * CH;
    const int tid = threadIdx.x;
    if (tid < CH * 2) {
        const int t = tid >> 1, half = (tid & 1) * 8;
        uint4 qv = *(const uint4*)(dbl + (size_t)(g0 + t) * DXP + DTR + half);
        float tmp[8]; unp8(qv, tmp);
        *(float4*)&sB[t * 16 + half]     = *(float4*)&tmp[0];
        *(float4*)&sB[t * 16 + half + 4] = *(float4*)&tmp[4];
    }
    __syncthreads();
    const int lane = tid & 63, w = tid >> 6;   // w = state quad (0..3)
    const int c = blockIdx.y * 64 + lane;      // 64 channels per block
    const int n0 = w * 4;
    const int fa = *flagA;

    float A[4];
    #pragma unroll
    for (int k = 0; k < 4; ++k) A[k] = nA[aoff + (n0 + k) * DI + c];
    const float a1 = nA[aoff + c];             // state-0 A for this channel
    float h[4] = {0.f, 0.f, 0.f, 0.f};
    float sdt = 0.f;

    u16 xu = xcb[(size_t)g0 * DI + c];
    u16 du = dtb[(size_t)g0 * DI + c];

    auto body = [&](auto tag) {
        constexpr bool FA = decltype(tag)::value;
        for (int t = 0; t < CH; ++t) {
            const float x = b2f(xu), dtv = b2f(du);
            if (t + 1 < CH) {
                xu = xcb[(size_t)(g0 + t + 1) * DI + c];
                du = dtb[(size_t)(g0 + t + 1) * DI + c];
            }
            const float4 Bv = *(const float4*)&sB[t * 16 + n0];   // broadcast
            const float dtx = dtv * x;
            sdt += dtv;
            float dA[4];
            if constexpr (FA) {
                const float e1 = __expf(dtv * a1);
                const float e2 = e1 * e1, e4 = e2 * e2, e8 = e4 * e4;
                const float base = (w == 0) ? 1.f : (w == 1) ? e4 : (w == 2) ? e8 : e8 * e4;
                dA[0] = base * e1; dA[1] = dA[0] * e1;
                dA[2] = dA[1] * e1; dA[3] = dA[2] * e1;
            } else {
                #pragma unroll
                for (int k = 0; k < 4; ++k) dA[k] = __expf(dtv * A[k]);
            }
            const float bw[4] = {Bv.x, Bv.y, Bv.z, Bv.w};
            #pragma unroll
            for (int k = 0; k < 4; ++k)
                h[k] = dA[k] * h[k] + dtx * bw[k];
        }
    };
    if (fa) body(BTrue{}); else body(BFalse{});

    #pragma unroll
    for (int k = 0; k < 4; ++k) {
        const size_t idx = ((size_t)ch * 16 + n0 + k) * DI + c;
        Pb[idx] = __expf(A[k] * sdt);          // prod_t exp(A dt_t) = exp(A*sum)
        Sb[idx] = h[k];
    }
}

__global__ __launch_bounds__(256)
void scan_part2(const float* __restrict__ Pb, const float* __restrict__ Sb,
                float* __restrict__ Hin) {
    const int s = blockIdx.x;                         // subject
    const int qd = blockIdx.y * 256 + threadIdx.x;    // n*DI + c  (< 16*DI)
    const int j0 = d_OFF[s] / CH;
    const int cnt = (d_OFF[s + 1] - d_OFF[s]) / CH;
    float h = 0.f;
    for (int j = 0; j < cnt; ++j) {
        const size_t idx = (size_t)(j0 + j) * (16 * DI) + qd;
        const float p = Pb[idx], sv = Sb[idx];
        Hin[idx] = h;
        h = p * h + sv;
    }
}

__global__ __launch_bounds__(256)
void scan_part3(const u16* __restrict__ xcb, const u16* __restrict__ dtb,
                const u16* __restrict__ xz, const u16* __restrict__ dbl,
                const float* __restrict__ nA, int aoff,
                const void* __restrict__ Dp, int doff,
                const float* __restrict__ Hin, u16* __restrict__ yb,
                const int* __restrict__ flagA, const int* __restrict__ flagp) {
    __shared__ float sBC[CH * 32];
    const int f32f = *flagp;
    const int ch = blockIdx.x;
    const int g0 = ch * CH;
    const int tid = threadIdx.x;
    if (tid < CH * 4) {
        const int t = tid >> 2, r = (tid & 3) * 8;
        uint4 qv = *(const uint4*)(dbl + (size_t)(g0 + t) * DXP + DTR + r);
        float tmp[8]; unp8(qv, tmp);
        *(float4*)&sBC[t * 32 + r]     = *(float4*)&tmp[0];
        *(float4*)&sBC[t * 32 + r + 4] = *(float4*)&tmp[4];
    }
    __syncthreads();
    const int lane = tid & 63, w = tid >> 6;
    const int c = (blockIdx.y * 4 + w) * 64 + lane;   // 256 channels/block
    const int fa = *flagA;

    float A[16];
    #pragma unroll
    for (int n = 0; n < 16; ++n) A[n] = nA[aoff + n * DI + c];
    const float a1 = A[0];
    const float Dv = ldin(Dp, (size_t)doff + c, f32f);
    float h[16];
    #pragma unroll
    for (int n = 0; n < 16; ++n) h[n] = Hin[((size_t)ch * 16 + n) * DI + c];

    u16 xu = xcb[(size_t)g0 * DI + c];
    u16 du = dtb[(size_t)g0 * DI + c];
    u16 zu = xz[(size_t)g0 * (2 * DI) + DI + c];

    auto body = [&](auto tag) {
        constexpr bool FA = decltype(tag)::value;
        for (int t = 0; t < CH; ++t) {
            const float x = b2f(xu), dtv = b2f(du), z = b2f(zu);
            if (t + 1 < CH) {
                xu = xcb[(size_t)(g0 + t + 1) * DI + c];
                du = dtb[(size_t)(g0 + t + 1) * DI + c];
                zu = xz[(size_t)(g0 + t + 1) * (2 * DI) + DI + c];
            }
            float Bv[16], Cvv[16];
            *(float4*)&Bv[0]   = *(const float4*)&sBC[t * 32 + 0];
            *(float4*)&Bv[4]   = *(const float4*)&sBC[t * 32 + 4];
            *(float4*)&Bv[8]   = *(const float4*)&sBC[t * 32 + 8];
            *(float4*)&Bv[12]  = *(const float4*)&sBC[t * 32 + 12];
            *(float4*)&Cvv[0]  = *(const float4*)&sBC[t * 32 + 16];
            *(float4*)&Cvv[4]  = *(const float4*)&sBC[t * 32 + 20];
            *(float4*)&Cvv[8]  = *(const float4*)&sBC[t * 32 + 24];
            *(float4*)&Cvv[12] = *(const float4*)&sBC[t * 32 + 28];
            const float dtx = dtv * x;
            float acc = 0.f;
            if constexpr (FA) {
                const float e1 = __expf(dtv * a1);
                float ep[17];
                ep[1] = e1;
                #pragma unroll
                for (int k = 2; k <= 16; ++k) ep[k] = ep[k >> 1] * ep[k - (k >> 1)];
                #pragma unroll
                for (int n = 0; n < 16; ++n) {
                    h[n] = ep[n + 1] * h[n] + dtx * Bv[n];
                    acc += h[n] * Cvv[n];
                }
            } else {
                #pragma unroll
                for (int n = 0; n < 16; ++n) {
                    const float dA = __expf(dtv * A[n]);
                    h[n] = dA * h[n] + dtx * Bv[n];
                    acc += h[n] * Cvv[n];
                }
            }
            const float sig = 1.f / (1.f + __expf(-z));
            yb[(size_t)(g0 + t) * DI + c] = f2b((acc + x * Dv) * (z * sig));
        }
    };
    if (fa) body(BTrue{}); else body(BFalse{});
}

extern "C" void kernel_launch(void* const* d_in, const int* in_sizes, int n_in,
                              void* d_out, int out_size, void* d_ws, size_t ws_size,
                              hipStream_t stream) {
    const int*  tokens     = (const int*)d_in[0];
    const void* embed      = d_in[1];
    const void* in_norm_w  = d_in[2];
    const void* out_norm_w = d_in[3];
    const void* norm_w     = d_in[4];
    const void* in_proj_w  = d_in[5];
    const void* conv_w     = d_in[6];
    const void* conv_b     = d_in[7];
    const void* x_proj_w   = d_in[8];
    const void* dt_proj_w  = d_in[9];
    const void* dt_proj_b  = d_in[10];
    const void* A_log      = d_in[11];
    const void* D_param    = d_in[12];
    const void* out_proj_w = d_in[13];
    const void* norm_f_w   = d_in[14];

    char* ws = (char*)d_ws;
    float* h    = (float*)(ws);                     // MPAD*768*4  = 21,233,664
    u16* normed = (u16*)(ws + 21233664);            // MPAD*768*2 = 10,616,832 region
    u16* xz     = (u16*)(ws + 31850496);            // MPAD*3072*2 (out_proj partial alias)
    u16* xcb    = (u16*)(ws + 74317824);            // MPAD*1536*2
    u16* dbl    = (u16*)(ws + 95551488);            // MPAD*80*2
    u16* dtb    = (u16*)(ws + 96657408);            // MPAD*1536*2
    u16* yb     = (u16*)(ws + 117891072);           // MPAD*1536*2 (aliases: Sb, x_proj partials)
    u16* w_ip   = (u16*)(ws + 139124736);           // 2*3072*768  bf16
    u16* w_op   = (u16*)(ws + 148561920);           // 2*768*1536  bf16
    u16* w_xp   = (u16*)(ws + 153280512);           // 2*80*1536   bf16
    u16* w_dtp  = (u16*)(ws + 153772032);           // 2*6*1536*8  bf16 planar [l][jb][c][8]
    int* flag   = (int*)(ws + 154165248);
    int* flagA  = (int*)(ws + 154165252);
    float* cwT  = (float*)(ws + 154165504);         // 2*4*1536 f32
    float* cbF  = (float*)(ws + 154214656);         // 2*1536 f32
    float* nA   = (float*)(ws + 154226944);         // 2*16*1536 f32 -> end 154,423,552
    // Pb/Hin live in the normed region: NCH*16*DI*4 = 10,518,528 <= 10,616,832 (CH=64 only!)
    float* Pb  = (float*)normed;   // scan pass1 out / pass2 in; Hin overwrites in pass2
    float* Sb  = (float*)yb;       // scan pass1 out / pass2 in (region = 21,233,664 B)
    float* Hin = (float*)normed;
    float* Pxp = (float*)yb;       // x_proj split-K partials (yb dead there)
    float* Pop = (float*)xz;       // out_proj partial (single slab, 21.2 MB)

    detect_dtype<<<1, 64, 0, stream>>>((const u16*)embed, flag);

    cvt_any<<<(2 * 2 * DI * DM + 255) / 256, 256, 0, stream>>>(in_proj_w,  w_ip, 2 * 2 * DI * DM, flag);
    cvt_any<<<(2 * DM * DI + 255) / 256, 256, 0, stream>>>(out_proj_w, w_op, 2 * DM * DI, flag);
    cvt_any<<<(2 * DXP * DI + 255) / 256, 256, 0, stream>>>(x_proj_w,  w_xp, 2 * DXP * DI, flag);
    cvt_dtp<<<(2 * 6 * DI * 8 + 255) / 256, 256, 0, stream>>>(dt_proj_w, w_dtp, flag);
    prep_conv<<<(2 * 16 * DI + 255) / 256, 256, 0, stream>>>(conv_w, conv_b, A_log, cwT, cbF, nA, flag);
    chk_A<<<1, 256, 0, stream>>>(nA, flagA);

    embed_rms2<<<TOTAL, 256, 0, stream>>>(tokens, embed, in_norm_w, norm_w, h, normed, flag);

    for (int l = 0; l < 2; ++l) {
        // in_proj: [MPAD,768] x [3072,768]^T -> xz   (24 K-tiles, even)
        gemm_bt<0, 128><<<dim3(MPAD / 128, 3072 / 128, 1), 256, 0, stream>>>(
            normed, w_ip + (size_t)l * 2 * DI * DM, xz, nullptr, flag,
            MPAD, 2 * DI, DM, DM, DM, 2 * DI, DM);
        conv_silu<<<(TOTAL * (DI / 2) + 255) / 256, 256, 0, stream>>>(
            xz, cwT + (size_t)l * 4 * DI, cbF + (size_t)l * DI, xcb);
        // x_proj: [MPAD,1536] x [80,1536]^T, split-K 8 (6 K-tiles each, even)
        gemm_bt<3, 64><<<dim3(MPAD / 128, 2, 8), 256, 0, stream>>>(
            xcb, w_xp + (size_t)l * DXP * DI, nullptr, Pxp, flag,
            MPAD, DXP, DI, DI, DI, DXP, DI / 8);
        // fused: partial-reduce -> dbl  +  dt_proj(rank-48) + softplus -> dtb
        reduce_xp_dt<<<MPAD / 8, 256, 0, stream>>>(
            dbl, dtb, Pxp, w_dtp + (size_t)l * 6 * DI * 8, dt_proj_b, l * DI, flag);
        // chunk-parallel selective scan (CH=64)
        scan_part1<<<dim3(NCH, DI / 64), 256, 0, stream>>>(
            xcb, dtb, dbl, nA, l * 16 * DI, Pb, Sb, flagA);
        scan_part2<<<dim3(NSUBJ, 16 * DI / 256), 256, 0, stream>>>(Pb, Sb, Hin);
        scan_part3<<<dim3(NCH, 6), 256, 0, stream>>>(
            xcb, dtb, xz, dbl, nA, l * 16 * DI, D_param, l * DI, Hin, yb, flagA, flag);
        // out_proj: [MPAD,1536] x [768,1536]^T, single K slab (48 K-tiles, even)
        gemm_bt<3, 64><<<dim3(MPAD / 128, DM / 64, 1), 256, 0, stream>>>(
            yb, w_op + (size_t)l * DM * DI, nullptr, Pop, flag,
            MPAD, DM, DI, DI, DI, DM, DI);
        // fused residual-add + norm (layer boundary / final)
        if (l == 0)
            reduce_out_rms<<<TOTAL, 256, 0, stream>>>(h, Pop, norm_w, DM, normed, flag);
        else
            reduce_out_final<<<TOTAL, 256, 0, stream>>>(h, Pop, norm_f_w, out_norm_w, d_out, flag);
    }
}

// Round 11
// 734.311 us; speedup vs baseline: 1.0106x; 1.0106x over previous
//
#include <hip/hip_runtime.h>
#include <hip/hip_bf16.h>

typedef unsigned short u16;
typedef unsigned int u32;
typedef __attribute__((ext_vector_type(8))) short short8_t;   // 8 bf16 (4 VGPRs)
typedef __attribute__((ext_vector_type(4))) float f32x4;

// ---- static problem config ----
#define NSUBJ 8
#define TOTAL 6848
#define MPAD  6912          // 54 * 128
#define DM    768
#define DI    1536
#define DS    16
#define DTR   48
#define DXP   80            // DTR + 2*DS
#define EPSN  1e-5f
#define CH    64            // scan chunk length (R8 lesson: CH=32 overflows the
                            // Pb/Hin alias region: NCH*16*DI*4 must fit MPAD*768*2)
#define NCH   107           // TOTAL / CH

__constant__ int d_OFF[NSUBJ + 1] = {0, 1024, 1920, 2688, 3712, 4224, 4864, 5824, 6848};

struct BTrue  { static constexpr bool value = true;  };
struct BFalse { static constexpr bool value = false; };

// ---- helpers ----
__device__ __forceinline__ float b2f(u16 u) {
    return __uint_as_float(((u32)u) << 16);
}
__device__ __forceinline__ u16 f2b(float f) {
    u32 u = __float_as_uint(f);
    u32 r = (u + 0x7FFFu + ((u >> 16) & 1u)) >> 16;
    return (u16)r;
}
__device__ __forceinline__ float ldin(const void* p, size_t i, int f32f) {
    return f32f ? ((const float*)p)[i] : b2f(((const u16*)p)[i]);
}

__device__ __forceinline__ void unp8(uint4 v, float* o) {
    u32 a0 = v.x, a1 = v.y, a2 = v.z, a3 = v.w;
    o[0] = __uint_as_float(a0 << 16);  o[1] = __uint_as_float(a0 & 0xFFFF0000u);
    o[2] = __uint_as_float(a1 << 16);  o[3] = __uint_as_float(a1 & 0xFFFF0000u);
    o[4] = __uint_as_float(a2 << 16);  o[5] = __uint_as_float(a2 & 0xFFFF0000u);
    o[6] = __uint_as_float(a3 << 16);  o[7] = __uint_as_float(a3 & 0xFFFF0000u);
}

// async global -> LDS, 16B per lane; LDS dest must be wave-uniform base + lane*16
__device__ __forceinline__ void gld16(const u16* g, u16* l) {
    __builtin_amdgcn_global_load_lds(
        (const __attribute__((address_space(1))) void*)g,
        (__attribute__((address_space(3))) void*)l, 16, 0, 0);
}

// counted-vmcnt wait + raw barrier + scheduling fences (rule #18: fence both sides)
template <int N>
__device__ __forceinline__ void waitbar() {
    __builtin_amdgcn_sched_barrier(0);
    if constexpr (N == 0)      asm volatile("s_waitcnt vmcnt(0)" ::: "memory");
    else if constexpr (N == 3) asm volatile("s_waitcnt vmcnt(3)" ::: "memory");
    else                       asm volatile("s_waitcnt vmcnt(4)" ::: "memory");
    __builtin_amdgcn_s_barrier();
    __builtin_amdgcn_sched_barrier(0);
}

__device__ __forceinline__ float block_sum(float v) {
    __shared__ float sbuf[8];
    __syncthreads();
    #pragma unroll
    for (int o = 32; o > 0; o >>= 1) v += __shfl_down(v, o, 64);
    const int lane = threadIdx.x & 63, w = threadIdx.x >> 6;
    if (lane == 0) sbuf[w] = v;
    __syncthreads();
    if (threadIdx.x == 0) sbuf[4] = sbuf[0] + sbuf[1] + sbuf[2] + sbuf[3];
    __syncthreads();
    return sbuf[4];
}

// ---- dtype detection ----
__global__ void detect_dtype(const u16* __restrict__ probe, int* __restrict__ flag) {
    const int lane = threadIdx.x;
    int cnt = 0;
    for (int i = 0; i < 32; ++i) {
        const u16 v = probe[lane * 32 + i];
        if (((v >> 7) & 0xFF) >= 0x90) cnt++;
    }
    #pragma unroll
    for (int o = 32; o > 0; o >>= 1) cnt += __shfl_down(cnt, o, 64);
    if (lane == 0) *flag = (cnt > 64) ? 1 : 0;
}

// ---- weight -> bf16 ws copy (convert if f32, plain copy if bf16) ----
__global__ void cvt_any(const void* __restrict__ src, u16* __restrict__ dst, int n,
                        const int* __restrict__ flagp) {
    const int f32f = *flagp;
    const int i = blockIdx.x * 256 + threadIdx.x;
    if (i < n) dst[i] = f32f ? f2b(((const float*)src)[i]) : ((const u16*)src)[i];
}

// ---- dt_proj weights repacked planar: dst[l][jb][c][8] bf16, jb = dt-rank chunk (48 = 6*8) ----
__global__ void cvt_dtp(const void* __restrict__ src, u16* __restrict__ dst,
                        const int* __restrict__ flagp) {
    const int f32f = *flagp;
    const int i = blockIdx.x * 256 + threadIdx.x;
    if (i >= 2 * 6 * DI * 8) return;
    const int j = i & 7;
    const int c = (i >> 3) % DI;
    const int jb = ((i >> 3) / DI) % 6;
    const int l = i / (8 * DI * 6);
    dst[i] = f2b(ldin(src, ((size_t)(l * DI + c)) * DTR + jb * 8 + j, f32f));
}

// ---- precompute: conv weights [l][tap][c] f32, conv bias f32, nA = -exp(A_log) [l][n][c] ----
__global__ void prep_conv(const void* __restrict__ cw, const void* __restrict__ cb,
                          const void* __restrict__ A_log,
                          float* __restrict__ cwT, float* __restrict__ cbF,
                          float* __restrict__ nA, const int* __restrict__ flagp) {
    const int f32f = *flagp;
    const int i = blockIdx.x * 256 + threadIdx.x;
    if (i < 2 * 4 * DI) {
        const int l = i / (4 * DI), r = i - l * 4 * DI;
        const int tap = r / DI, c = r - tap * DI;
        cwT[i] = ldin(cw, (size_t)l * DI * 4 + (size_t)c * 4 + tap, f32f);
    }
    if (i < 2 * DI) cbF[i] = ldin(cb, i, f32f);
    if (i < 2 * 16 * DI) {
        const int l = i / (16 * DI), r = i - l * 16 * DI;
        const int n = r / DI, c = r - n * DI;
        nA[i] = -__expf(ldin(A_log, (size_t)l * DI * DS + (size_t)c * DS + n, f32f));
    }
}

// ---- check A[n] = (n+1)*A[0] structure (Mamba default init) ----
__global__ void chk_A(const float* __restrict__ nA, int* __restrict__ flagA) {
    int viol = 0;
    for (int i = threadIdx.x; i < 2 * 16 * DI; i += 256) {
        const int l = i / (16 * DI);
        const int rem = i - l * 16 * DI;
        const int n = rem / DI;
        const int c = rem - n * DI;
        const float a1 = nA[l * 16 * DI + c];
        const float want = (float)(n + 1) * a1;
        const float got = nA[i];
        if (fabsf(got - want) > 1e-4f * fabsf(want) + 1e-6f) viol = 1;
    }
    const float v = block_sum((float)viol);
    if (threadIdx.x == 0) *flagA = (v == 0.f) ? 1 : 0;
}

// ---- fused: embedding gather + rmsnorm(in_norm) -> h f32 AND rmsnorm(norm_w[0]) -> bf16 normed ----
__global__ void embed_rms2(const int* __restrict__ tokens, const void* __restrict__ embed,
                           const void* __restrict__ w_in, const void* __restrict__ w_l0,
                           float* __restrict__ h, u16* __restrict__ normed,
                           const int* __restrict__ flagp) {
    const int f32f = *flagp;
    const int f = blockIdx.x;
    const int tid = threadIdx.x;
    const int row = tokens[f];
    float v[3]; float ss = 0.f;
    #pragma unroll
    for (int i = 0; i < 3; ++i) {
        v[i] = ldin(embed, (size_t)row * DM + tid + 256 * i, f32f);
        ss += v[i] * v[i];
    }
    float tot = block_sum(ss);
    float rs = rsqrtf(tot * (1.f / DM) + EPSN);
    float ss2 = 0.f;
    #pragma unroll
    for (int i = 0; i < 3; ++i) {
        v[i] = v[i] * rs * ldin(w_in, tid + 256 * i, f32f);
        h[(size_t)f * DM + tid + 256 * i] = v[i];
        ss2 += v[i] * v[i];
    }
    tot = block_sum(ss2);
    rs = rsqrtf(tot * (1.f / DM) + EPSN);
    #pragma unroll
    for (int i = 0; i < 3; ++i)
        normed[(size_t)f * DM + tid + 256 * i] =
            f2b(v[i] * rs * ldin(w_l0, tid + 256 * i, f32f));
}

// ---- MFMA GEMM: C[M,N] = A[M,K](lda) * B[N,K](ldb)^T, bf16 in, f32 acc ----
// GEMM ledger (in_proj dispatch): 2-phase 57.8us | 3-buf counted-vmcnt 57.4us
// | +band-swizzle 63.9us (FETCH -28% but slower; not BW-bound -> reverted)
// | BK=64 60.2us (64KB LDS -> 2 blocks/CU, occupancy 25->17% -> reverted).
// R11: restore the best: 3-buffer counted-vmcnt, linear block order, 48KB LDS.
// EPI: 0 = store bf16; 3 = f32 partial Pbuf[z][M][N]
template <int EPI, int TN_>
__global__ __launch_bounds__(256)
void gemm_bt(const u16* __restrict__ A, const u16* __restrict__ B,
             void* __restrict__ Cv, float* __restrict__ Pbuf,
             const int* __restrict__ flagp,
             int M, int N, int K, int lda, int ldb, int ldc, int ksplit) {
    constexpr int NJ = TN_ / 32;
    constexpr int LPS = (TN_ == 128) ? 4 : 3;   // loads per stage per thread
    __shared__ u16 sA[3][128 * 32];
    __shared__ u16 sB[3][TN_ * 32];
    const int tid = threadIdx.x;
    const int bm = blockIdx.x * 128;
    const int bn = blockIdx.y * TN_;
    const int lane = tid & 63, w = tid >> 6;
    const int wm = (w >> 1) * 64;
    const int wn = (w & 1) * (TN_ / 2);
    const int lr = lane & 15;
    const int q = lane >> 4;
    const int sw = (q ^ (lr & 3)) * 8;          // swizzled k-slot (u16 elems)

    int oA[4]; int oB[NJ];
    #pragma unroll
    for (int i = 0; i < 4; ++i) oA[i] = (wm + i * 16 + lr) * 32 + sw;
    #pragma unroll
    for (int j = 0; j < NJ; ++j) oB[j] = (wn + j * 16 + lr) * 32 + sw;

    const int r0 = tid >> 2;
    const int kp = ((tid & 3) ^ (r0 & 3)) * 8;  // global k offset (elems)

    const u16* gA0 = A + (size_t)(bm + r0) * lda + kp;
    const u16* gA1 = A + (size_t)(bm + r0 + 64) * lda + kp;
    const u16* gB0 = B + (size_t)(bn + r0) * ldb + kp;
    const u16* gB1 = (TN_ == 128) ? (B + (size_t)(bn + r0 + 64) * ldb + kp) : nullptr;

    f32x4 acc[4][NJ];
    #pragma unroll
    for (int i = 0; i < 4; ++i)
        #pragma unroll
        for (int j = 0; j < NJ; ++j)
            acc[i][j] = (f32x4){0.f, 0.f, 0.f, 0.f};

    const int kb = blockIdx.z * ksplit;
    const int ke = (kb + ksplit < K) ? (kb + ksplit) : K;
    const int nt = (ke - kb) >> 5;              // K tiles (K multiple of 32)

    auto stage = [&](int b, int t) {
        const int k0 = kb + t * 32;
        gld16(gA0 + k0, &sA[b][tid * 8]);
        gld16(gA1 + k0, &sA[b][(256 + tid) * 8]);
        gld16(gB0 + k0, &sB[b][tid * 8]);
        if constexpr (TN_ == 128) gld16(gB1 + k0, &sB[b][(256 + tid) * 8]);
    };

    // prologue: 2 tiles in flight; wait only for tile 0
    stage(0, 0);
    if (nt > 1) { stage(1, 1); waitbar<LPS>(); }
    else        { waitbar<0>(); }

    int cur = 0;
    for (int t = 0; t < nt; ++t) {
        short8_t af[4], bfr[NJ];
        #pragma unroll
        for (int i = 0; i < 4; ++i) af[i] = *(const short8_t*)&sA[cur][oA[i]];
        #pragma unroll
        for (int j = 0; j < NJ; ++j) bfr[j] = *(const short8_t*)&sB[cur][oB[j]];
        __builtin_amdgcn_sched_barrier(0);      // ds_reads stay before the stage

        if (t + 2 < nt) {
            int b2 = cur + 2; if (b2 >= 3) b2 -= 3;
            stage(b2, t + 2);
        }

        #pragma unroll
        for (int i = 0; i < 4; ++i)
            #pragma unroll
            for (int j = 0; j < NJ; ++j)
                acc[i][j] = __builtin_amdgcn_mfma_f32_16x16x32_bf16(af[i], bfr[j], acc[i][j], 0, 0, 0);

        if (t + 1 < nt) {
            if (t + 2 < nt) waitbar<LPS>();     // leave tile t+2 in flight
            else            waitbar<0>();       // last prefetch: drain
        }
        cur = (cur == 2) ? 0 : cur + 1;
    }

    // epilogue: C/D layout col=lane&15, row=(lane>>4)*4 + reg   [verified m89/m91]
    const int cr = (lane >> 4) * 4;
    const int cc = lane & 15;
    #pragma unroll
    for (int i = 0; i < 4; ++i) {
        const int gm0 = bm + wm + i * 16 + cr;
        #pragma unroll
        for (int j = 0; j < NJ; ++j) {
            const int gn = bn + wn + j * 16 + cc;
            if (gn < N) {
                #pragma unroll
                for (int r = 0; r < 4; ++r) {
                    float v = acc[i][j][r];
                    const size_t idx = (size_t)(gm0 + r) * ldc + gn;
                    if (EPI == 0) {
                        ((u16*)Cv)[idx] = f2b(v);
                    } else {
                        Pbuf[(size_t)blockIdx.z * M * N + idx] = v;
                    }
                }
            }
        }
    }
}

// ---- fused: reduce 8 x_proj split-K partials -> bf16 dbl [MPAD,80]
//      AND dt_proj(rank-48) + softplus -> dtb [MPAD,1536].
__global__ __launch_bounds__(256)
void reduce_xp_dt(u16* __restrict__ dbl, u16* __restrict__ dtb,
                  const float* __restrict__ P, const u16* __restrict__ wdt,
                  const void* __restrict__ bias, int bias_off,
                  const int* __restrict__ flagp) {
    __shared__ float sdt[8 * DTR];              // [tok][48] f32
    const int f32f = *flagp;
    const int tid = threadIdx.x;
    const int g0 = blockIdx.x * 8;              // first token row of this block

    #pragma unroll
    for (int it = 0; it < 3; ++it) {
        const int idx = tid + it * 256;
        if (idx < 8 * DXP) {
            const size_t base = (size_t)g0 * DXP + idx;
            float s = 0.f;
            #pragma unroll
            for (int z = 0; z < 8; ++z) s += P[(size_t)z * MPAD * DXP + base];
            dbl[base] = f2b(s);
            const int tok = idx / DXP, col = idx - tok * DXP;
            if (col < DTR) sdt[tok * DTR + col] = s;
        }
    }
    __syncthreads();

    #pragma unroll 1
    for (int p = 0; p < 2; ++p) {
        float acc[3][8];
        #pragma unroll
        for (int kc = 0; kc < 3; ++kc)
            #pragma unroll
            for (int t = 0; t < 8; ++t) acc[kc][t] = 0.f;

        #pragma unroll 1
        for (int jb = 0; jb < 6; ++jb) {        // 6 chunks of 8 dt-rank dims
            float w[3][8];
            #pragma unroll
            for (int kc = 0; kc < 3; ++kc) {
                const int c = tid + (p * 3 + kc) * 256;
                const uint4 wv = *(const uint4*)(wdt + ((size_t)jb * DI + c) * 8);
                unp8(wv, w[kc]);
            }
            #pragma unroll
            for (int t = 0; t < 8; ++t) {
                float sj[8];
                *(float4*)&sj[0] = *(const float4*)&sdt[t * DTR + jb * 8];
                *(float4*)&sj[4] = *(const float4*)&sdt[t * DTR + jb * 8 + 4];
                #pragma unroll
                for (int kc = 0; kc < 3; ++kc)
                    #pragma unroll
                    for (int j = 0; j < 8; ++j)
                        acc[kc][t] += w[kc][j] * sj[j];
            }
        }

        #pragma unroll
        for (int kc = 0; kc < 3; ++kc) {
            const int c = tid + (p * 3 + kc) * 256;
            const float bv = ldin(bias, (size_t)(bias_off + c), f32f);
            #pragma unroll
            for (int t = 0; t < 8; ++t) {
                float v = acc[kc][t] + bv;
                v = (v > 20.f) ? v : __logf(1.f + __expf(v));
                dtb[(size_t)(g0 + t) * DI + c] = f2b(v);
            }
        }
    }
}

// ---- fused: h += out_proj partial (single slab) AND rmsnorm -> bf16 normed ----
__global__ void reduce_out_rms(float* __restrict__ h, const float* __restrict__ P,
                               const void* __restrict__ w, int woff,
                               u16* __restrict__ out, const int* __restrict__ flagp) {
    const int f32f = *flagp;
    const int f = blockIdx.x;
    const int tid = threadIdx.x;
    float v[3]; float ss = 0.f;
    #pragma unroll
    for (int i = 0; i < 3; ++i) {
        const size_t idx = (size_t)f * DM + tid + 256 * i;
        const float a = h[idx] + P[idx];
        h[idx] = a; v[i] = a; ss += a * a;
    }
    const float tot = block_sum(ss);
    const float rs = rsqrtf(tot * (1.f / DM) + EPSN);
    #pragma unroll
    for (int i = 0; i < 3; ++i)
        out[(size_t)f * DM + tid + 256 * i] =
            f2b(v[i] * rs * ldin(w, woff + tid + 256 * i, f32f));
}

// ---- fused: h += partial AND double rmsnorm -> d_out (end fusion) ----
__global__ void reduce_out_final(const float* __restrict__ h, const float* __restrict__ P,
                                 const void* __restrict__ wf, const void* __restrict__ wo,
                                 void* __restrict__ out, const int* __restrict__ flagp) {
    const int f32f = *flagp;
    const int f = blockIdx.x;
    const int tid = threadIdx.x;
    float v[3]; float ss = 0.f;
    #pragma unroll
    for (int i = 0; i < 3; ++i) {
        const size_t idx = (size_t)f * DM + tid + 256 * i;
        v[i] = h[idx] + P[idx];
        ss += v[i] * v[i];
    }
    float tot = block_sum(ss);
    float rs = rsqrtf(tot * (1.f / DM) + EPSN);
    float ss2 = 0.f;
    #pragma unroll
    for (int i = 0; i < 3; ++i) {
        v[i] = v[i] * rs * ldin(wf, tid + 256 * i, f32f);
        ss2 += v[i] * v[i];
    }
    tot = block_sum(ss2);
    rs = rsqrtf(tot * (1.f / DM) + EPSN);
    #pragma unroll
    for (int i = 0; i < 3; ++i) {
        const float r = v[i] * rs * ldin(wo, tid + 256 * i, f32f);
        const size_t idx = (size_t)f * DM + tid + 256 * i;
        if (f32f) ((float*)out)[idx] = r;
        else      ((u16*)out)[idx] = f2b(r);
    }
}

// ---- causal depthwise conv(K=4) + bias + silu; fully coalesced ----
__global__ void conv_silu(const u16* __restrict__ xz, const float* __restrict__ cwT,
                          const float* __restrict__ cbF, u16* __restrict__ xc) {
    const int gid = blockIdx.x * 256 + threadIdx.x;
    if (gid >= TOTAL * (DI / 2)) return;
    const int f = gid / (DI / 2);
    const int c = (gid - f * (DI / 2)) * 2;
    int s = 0;
    while (f >= d_OFF[s + 1]) s++;
    const int t = f - d_OFF[s];

    float2 acc = *(const float2*)(cbF + c);
    #pragma unroll
    for (int j = 0; j < 4; ++j) {
        if (t - 3 + j >= 0) {
            const u32 xp = *(const u32*)(xz + (size_t)(f - 3 + j) * (2 * DI) + c);
            const float2 wv = *(const float2*)(cwT + j * DI + c);
            acc.x += __uint_as_float(xp << 16) * wv.x;
            acc.y += __uint_as_float(xp & 0xFFFF0000u) * wv.y;
        }
    }
    const float s0 = acc.x / (1.f + __expf(-acc.x));
    const float s1 = acc.y / (1.f + __expf(-acc.y));
    *(u32*)(xc + (size_t)f * DI + c) = (u32)f2b(s0) | ((u32)f2b(s1) << 16);
}

// ==================== chunk-parallel selective scan (3 passes) ====================
__global__ __launch_bounds__(256)
void scan_part1(const u16* __restrict__ xcb, const u16* __restrict__ dtb,
                const u16* __restrict__ dbl,
                const float* __restrict__ nA, int aoff,
                float* __restrict__ Pb, float* __restrict__ Sb,
                const int* __restrict__ flagA) {
    __shared__ float sB[CH * 16];
    const int ch = blockIdx.x;
    const int g0 = ch * CH;
    const int tid = threadIdx.x;
    if (tid < CH * 2) {
        const int t = tid >> 1, half = (tid & 1) * 8;
        uint4 qv = *(const uint4*)(dbl + (size_t)(g0 + t) * DXP + DTR + half);
        float tmp[8]; unp8(qv, tmp);
        *(float4*)&sB[t * 16 + half]     = *(float4*)&tmp[0];
        *(float4*)&sB[t * 16 + half + 4] = *(float4*)&tmp[4];
    }
    __syncthreads();
    const int lane = tid & 63, w = tid >> 6;   // w = state quad (0..3)
    const int c = blockIdx.y * 64 + lane;      // 64 channels per block
    const int n0 = w * 4;
    const int fa = *flagA;

    float A[4];
    #pragma unroll
    for (int k = 0; k < 4; ++k) A[k] = nA[aoff + (n0 + k) * DI + c];
    const float a1 = nA[aoff + c];             // state-0 A for this channel
    float h[4] = {0.f, 0.f, 0.f, 0.f};
    float sdt = 0.f;

    u16 xu = xcb[(size_t)g0 * DI + c];
    u16 du = dtb[(size_t)g0 * DI + c];

    auto body = [&](auto tag) {
        constexpr bool FA = decltype(tag)::value;
        for (int t = 0; t < CH; ++t) {
            const float x = b2f(xu), dtv = b2f(du);
            if (t + 1 < CH) {
                xu = xcb[(size_t)(g0 + t + 1) * DI + c];
                du = dtb[(size_t)(g0 + t + 1) * DI + c];
            }
            const float4 Bv = *(const float4*)&sB[t * 16 + n0];   // broadcast
            const float dtx = dtv * x;
            sdt += dtv;
            float dA[4];
            if constexpr (FA) {
                const float e1 = __expf(dtv * a1);
                const float e2 = e1 * e1, e4 = e2 * e2, e8 = e4 * e4;
                const float base = (w == 0) ? 1.f : (w == 1) ? e4 : (w == 2) ? e8 : e8 * e4;
                dA[0] = base * e1; dA[1] = dA[0] * e1;
                dA[2] = dA[1] * e1; dA[3] = dA[2] * e1;
            } else {
                #pragma unroll
                for (int k = 0; k < 4; ++k) dA[k] = __expf(dtv * A[k]);
            }
            const float bw[4] = {Bv.x, Bv.y, Bv.z, Bv.w};
            #pragma unroll
            for (int k = 0; k < 4; ++k)
                h[k] = dA[k] * h[k] + dtx * bw[k];
        }
    };
    if (fa) body(BTrue{}); else body(BFalse{});

    #pragma unroll
    for (int k = 0; k < 4; ++k) {
        const size_t idx = ((size_t)ch * 16 + n0 + k) * DI + c;
        Pb[idx] = __expf(A[k] * sdt);          // prod_t exp(A dt_t) = exp(A*sum)
        Sb[idx] = h[k];
    }
}

__global__ __launch_bounds__(256)
void scan_part2(const float* __restrict__ Pb, const float* __restrict__ Sb,
                float* __restrict__ Hin) {
    const int s = blockIdx.x;                         // subject
    const int qd = blockIdx.y * 256 + threadIdx.x;    // n*DI + c  (< 16*DI)
    const int j0 = d_OFF[s] / CH;
    const int cnt = (d_OFF[s + 1] - d_OFF[s]) / CH;
    float h = 0.f;
    for (int j = 0; j < cnt; ++j) {
        const size_t idx = (size_t)(j0 + j) * (16 * DI) + qd;
        const float p = Pb[idx], sv = Sb[idx];
        Hin[idx] = h;
        h = p * h + sv;
    }
}

__global__ __launch_bounds__(256)
void scan_part3(const u16* __restrict__ xcb, const u16* __restrict__ dtb,
                const u16* __restrict__ xz, const u16* __restrict__ dbl,
                const float* __restrict__ nA, int aoff,
                const void* __restrict__ Dp, int doff,
                const float* __restrict__ Hin, u16* __restrict__ yb,
                const int* __restrict__ flagA, const int* __restrict__ flagp) {
    __shared__ float sBC[CH * 32];
    const int f32f = *flagp;
    const int ch = blockIdx.x;
    const int g0 = ch * CH;
    const int tid = threadIdx.x;
    if (tid < CH * 4) {
        const int t = tid >> 2, r = (tid & 3) * 8;
        uint4 qv = *(const uint4*)(dbl + (size_t)(g0 + t) * DXP + DTR + r);
        float tmp[8]; unp8(qv, tmp);
        *(float4*)&sBC[t * 32 + r]     = *(float4*)&tmp[0];
        *(float4*)&sBC[t * 32 + r + 4] = *(float4*)&tmp[4];
    }
    __syncthreads();
    const int lane = tid & 63, w = tid >> 6;
    const int c = (blockIdx.y * 4 + w) * 64 + lane;   // 256 channels/block
    const int fa = *flagA;

    float A[16];
    #pragma unroll
    for (int n = 0; n < 16; ++n) A[n] = nA[aoff + n * DI + c];
    const float a1 = A[0];
    const float Dv = ldin(Dp, (size_t)doff + c, f32f);
    float h[16];
    #pragma unroll
    for (int n = 0; n < 16; ++n) h[n] = Hin[((size_t)ch * 16 + n) * DI + c];

    u16 xu = xcb[(size_t)g0 * DI + c];
    u16 du = dtb[(size_t)g0 * DI + c];
    u16 zu = xz[(size_t)g0 * (2 * DI) + DI + c];

    auto body = [&](auto tag) {
        constexpr bool FA = decltype(tag)::value;
        for (int t = 0; t < CH; ++t) {
            const float x = b2f(xu), dtv = b2f(du), z = b2f(zu);
            if (t + 1 < CH) {
                xu = xcb[(size_t)(g0 + t + 1) * DI + c];
                du = dtb[(size_t)(g0 + t + 1) * DI + c];
                zu = xz[(size_t)(g0 + t + 1) * (2 * DI) + DI + c];
            }
            float Bv[16], Cvv[16];
            *(float4*)&Bv[0]   = *(const float4*)&sBC[t * 32 + 0];
            *(float4*)&Bv[4]   = *(const float4*)&sBC[t * 32 + 4];
            *(float4*)&Bv[8]   = *(const float4*)&sBC[t * 32 + 8];
            *(float4*)&Bv[12]  = *(const float4*)&sBC[t * 32 + 12];
            *(float4*)&Cvv[0]  = *(const float4*)&sBC[t * 32 + 16];
            *(float4*)&Cvv[4]  = *(const float4*)&sBC[t * 32 + 20];
            *(float4*)&Cvv[8]  = *(const float4*)&sBC[t * 32 + 24];
            *(float4*)&Cvv[12] = *(const float4*)&sBC[t * 32 + 28];
            const float dtx = dtv * x;
            float acc = 0.f;
            if constexpr (FA) {
                const float e1 = __expf(dtv * a1);
                float ep[17];
                ep[1] = e1;
                #pragma unroll
                for (int k = 2; k <= 16; ++k) ep[k] = ep[k >> 1] * ep[k - (k >> 1)];
                #pragma unroll
                for (int n = 0; n < 16; ++n) {
                    h[n] = ep[n + 1] * h[n] + dtx * Bv[n];
                    acc += h[n] * Cvv[n];
                }
            } else {
                #pragma unroll
                for (int n = 0; n < 16; ++n) {
                    const float dA = __expf(dtv * A[n]);
                    h[n] = dA * h[n] + dtx * Bv[n];
                    acc += h[n] * Cvv[n];
                }
            }
            const float sig = 1.f / (1.f + __expf(-z));
            yb[(size_t)(g0 + t) * DI + c] = f2b((acc + x * Dv) * (z * sig));
        }
    };
    if (fa) body(BTrue{}); else body(BFalse{});
}

extern "C" void kernel_launch(void* const* d_in, const int* in_sizes, int n_in,
                              void* d_out, int out_size, void* d_ws, size_t ws_size,
                              hipStream_t stream) {
    const int*  tokens     = (const int*)d_in[0];
    const void* embed      = d_in[1];
    const void* in_norm_w  = d_in[2];
    const void* out_norm_w = d_in[3];
    const void* norm_w     = d_in[4];
    const void* in_proj_w  = d_in[5];
    const void* conv_w     = d_in[6];
    const void* conv_b     = d_in[7];
    const void* x_proj_w   = d_in[8];
    const void* dt_proj_w  = d_in[9];
    const void* dt_proj_b  = d_in[10];
    const void* A_log      = d_in[11];
    const void* D_param    = d_in[12];
    const void* out_proj_w = d_in[13];
    const void* norm_f_w   = d_in[14];

    char* ws = (char*)d_ws;
    float* h    = (float*)(ws);                     // MPAD*768*4  = 21,233,664
    u16* normed = (u16*)(ws + 21233664);            // MPAD*768*2 = 10,616,832 region
    u16* xz     = (u16*)(ws + 31850496);            // MPAD*3072*2 (out_proj partial alias)
    u16* xcb    = (u16*)(ws + 74317824);            // MPAD*1536*2
    u16* dbl    = (u16*)(ws + 95551488);            // MPAD*80*2
    u16* dtb    = (u16*)(ws + 96657408);            // MPAD*1536*2
    u16* yb     = (u16*)(ws + 117891072);           // MPAD*1536*2 (aliases: Sb, x_proj partials)
    u16* w_ip   = (u16*)(ws + 139124736);           // 2*3072*768  bf16
    u16* w_op   = (u16*)(ws + 148561920);           // 2*768*1536  bf16
    u16* w_xp   = (u16*)(ws + 153280512);           // 2*80*1536   bf16
    u16* w_dtp  = (u16*)(ws + 153772032);           // 2*6*1536*8  bf16 planar [l][jb][c][8]
    int* flag   = (int*)(ws + 154165248);
    int* flagA  = (int*)(ws + 154165252);
    float* cwT  = (float*)(ws + 154165504);         // 2*4*1536 f32
    float* cbF  = (float*)(ws + 154214656);         // 2*1536 f32
    float* nA   = (float*)(ws + 154226944);         // 2*16*1536 f32 -> end 154,423,552
    // Pb/Hin live in the normed region: NCH*16*DI*4 = 10,518,528 <= 10,616,832 (CH=64 only!)
    float* Pb  = (float*)normed;   // scan pass1 out / pass2 in; Hin overwrites in pass2
    float* Sb  = (float*)yb;       // scan pass1 out / pass2 in (region = 21,233,664 B)
    float* Hin = (float*)normed;
    float* Pxp = (float*)yb;       // x_proj split-K partials (yb dead there)
    float* Pop = (float*)xz;       // out_proj partial (single slab, 21.2 MB)

    detect_dtype<<<1, 64, 0, stream>>>((const u16*)embed, flag);

    cvt_any<<<(2 * 2 * DI * DM + 255) / 256, 256, 0, stream>>>(in_proj_w,  w_ip, 2 * 2 * DI * DM, flag);
    cvt_any<<<(2 * DM * DI + 255) / 256, 256, 0, stream>>>(out_proj_w, w_op, 2 * DM * DI, flag);
    cvt_any<<<(2 * DXP * DI + 255) / 256, 256, 0, stream>>>(x_proj_w,  w_xp, 2 * DXP * DI, flag);
    cvt_dtp<<<(2 * 6 * DI * 8 + 255) / 256, 256, 0, stream>>>(dt_proj_w, w_dtp, flag);
    prep_conv<<<(2 * 16 * DI + 255) / 256, 256, 0, stream>>>(conv_w, conv_b, A_log, cwT, cbF, nA, flag);
    chk_A<<<1, 256, 0, stream>>>(nA, flagA);

    embed_rms2<<<TOTAL, 256, 0, stream>>>(tokens, embed, in_norm_w, norm_w, h, normed, flag);

    for (int l = 0; l < 2; ++l) {
        // in_proj: [MPAD,768] x [3072,768]^T -> xz
        gemm_bt<0, 128><<<dim3(MPAD / 128, 3072 / 128, 1), 256, 0, stream>>>(
            normed, w_ip + (size_t)l * 2 * DI * DM, xz, nullptr, flag,
            MPAD, 2 * DI, DM, DM, DM, 2 * DI, DM);
        conv_silu<<<(TOTAL * (DI / 2) + 255) / 256, 256, 0, stream>>>(
            xz, cwT + (size_t)l * 4 * DI, cbF + (size_t)l * DI, xcb);
        // x_proj: [MPAD,1536] x [80,1536]^T, split-K 8 -> f32 partials (in yb region)
        gemm_bt<3, 64><<<dim3(MPAD / 128, 2, 8), 256, 0, stream>>>(
            xcb, w_xp + (size_t)l * DXP * DI, nullptr, Pxp, flag,
            MPAD, DXP, DI, DI, DI, DXP, DI / 8);
        // fused: partial-reduce -> dbl  +  dt_proj(rank-48) + softplus -> dtb
        reduce_xp_dt<<<MPAD / 8, 256, 0, stream>>>(
            dbl, dtb, Pxp, w_dtp + (size_t)l * 6 * DI * 8, dt_proj_b, l * DI, flag);
        // chunk-parallel selective scan (CH=64)
        scan_part1<<<dim3(NCH, DI / 64), 256, 0, stream>>>(
            xcb, dtb, dbl, nA, l * 16 * DI, Pb, Sb, flagA);
        scan_part2<<<dim3(NSUBJ, 16 * DI / 256), 256, 0, stream>>>(Pb, Sb, Hin);
        scan_part3<<<dim3(NCH, 6), 256, 0, stream>>>(
            xcb, dtb, xz, dbl, nA, l * 16 * DI, D_param, l * DI, Hin, yb, flagA, flag);
        // out_proj: [MPAD,1536] x [768,1536]^T, single K slab
        gemm_bt<3, 64><<<dim3(MPAD / 128, DM / 64, 1), 256, 0, stream>>>(
            yb, w_op + (size_t)l * DM * DI, nullptr, Pop, flag,
            MPAD, DM, DI, DI, DI, DM, DI);
        // fused residual-add + norm (layer boundary / final)
        if (l == 0)
            reduce_out_rms<<<TOTAL, 256, 0, stream>>>(h, Pop, norm_w, DM, normed, flag);
        else
            reduce_out_final<<<TOTAL, 256, 0, stream>>>(h, Pop, norm_f_w, out_norm_w, d_out, flag);
    }
}

// Round 12
// 723.155 us; speedup vs baseline: 1.0262x; 1.0154x over previous
//
#include <hip/hip_runtime.h>
#include <hip/hip_bf16.h>

typedef unsigned short u16;
typedef unsigned int u32;
typedef __attribute__((ext_vector_type(8))) short short8_t;   // 8 bf16 (4 VGPRs)
typedef __attribute__((ext_vector_type(4))) float f32x4;

// ---- static problem config ----
#define NSUBJ 8
#define TOTAL 6848
#define MPAD  6912          // 54 * 128
#define DM    768
#define DI    1536
#define DS    16
#define DTR   48
#define DXP   80            // DTR + 2*DS
#define EPSN  1e-5f
#define CH    64            // scan chunk length (R8 lesson: CH=32 overflows the
                            // Pb/Hin alias region: NCH*16*DI*4 must fit MPAD*768*2)
#define NCH   107           // TOTAL / CH
#define NSPL  4             // x_proj split-K factor (R12: 8->4, halves partial traffic)

__constant__ int d_OFF[NSUBJ + 1] = {0, 1024, 1920, 2688, 3712, 4224, 4864, 5824, 6848};

struct BTrue  { static constexpr bool value = true;  };
struct BFalse { static constexpr bool value = false; };

// ---- helpers ----
__device__ __forceinline__ float b2f(u16 u) {
    return __uint_as_float(((u32)u) << 16);
}
__device__ __forceinline__ u16 f2b(float f) {
    u32 u = __float_as_uint(f);
    u32 r = (u + 0x7FFFu + ((u >> 16) & 1u)) >> 16;
    return (u16)r;
}
__device__ __forceinline__ float ldin(const void* p, size_t i, int f32f) {
    return f32f ? ((const float*)p)[i] : b2f(((const u16*)p)[i]);
}

__device__ __forceinline__ void unp8(uint4 v, float* o) {
    u32 a0 = v.x, a1 = v.y, a2 = v.z, a3 = v.w;
    o[0] = __uint_as_float(a0 << 16);  o[1] = __uint_as_float(a0 & 0xFFFF0000u);
    o[2] = __uint_as_float(a1 << 16);  o[3] = __uint_as_float(a1 & 0xFFFF0000u);
    o[4] = __uint_as_float(a2 << 16);  o[5] = __uint_as_float(a2 & 0xFFFF0000u);
    o[6] = __uint_as_float(a3 << 16);  o[7] = __uint_as_float(a3 & 0xFFFF0000u);
}

// async global -> LDS, 16B per lane; LDS dest must be wave-uniform base + lane*16
__device__ __forceinline__ void gld16(const u16* g, u16* l) {
    __builtin_amdgcn_global_load_lds(
        (const __attribute__((address_space(1))) void*)g,
        (__attribute__((address_space(3))) void*)l, 16, 0, 0);
}

// counted-vmcnt wait + raw barrier + scheduling fences (rule #18: fence both sides)
template <int N>
__device__ __forceinline__ void waitbar() {
    __builtin_amdgcn_sched_barrier(0);
    if constexpr (N == 0)      asm volatile("s_waitcnt vmcnt(0)" ::: "memory");
    else if constexpr (N == 3) asm volatile("s_waitcnt vmcnt(3)" ::: "memory");
    else                       asm volatile("s_waitcnt vmcnt(4)" ::: "memory");
    __builtin_amdgcn_s_barrier();
    __builtin_amdgcn_sched_barrier(0);
}

__device__ __forceinline__ float block_sum(float v) {
    __shared__ float sbuf[8];
    __syncthreads();
    #pragma unroll
    for (int o = 32; o > 0; o >>= 1) v += __shfl_down(v, o, 64);
    const int lane = threadIdx.x & 63, w = threadIdx.x >> 6;
    if (lane == 0) sbuf[w] = v;
    __syncthreads();
    if (threadIdx.x == 0) sbuf[4] = sbuf[0] + sbuf[1] + sbuf[2] + sbuf[3];
    __syncthreads();
    return sbuf[4];
}

// ---- dtype detection ----
__global__ void detect_dtype(const u16* __restrict__ probe, int* __restrict__ flag) {
    const int lane = threadIdx.x;
    int cnt = 0;
    for (int i = 0; i < 32; ++i) {
        const u16 v = probe[lane * 32 + i];
        if (((v >> 7) & 0xFF) >= 0x90) cnt++;
    }
    #pragma unroll
    for (int o = 32; o > 0; o >>= 1) cnt += __shfl_down(cnt, o, 64);
    if (lane == 0) *flag = (cnt > 64) ? 1 : 0;
}

// ---- weight -> bf16 ws copy (convert if f32, plain copy if bf16) ----
__global__ void cvt_any(const void* __restrict__ src, u16* __restrict__ dst, int n,
                        const int* __restrict__ flagp) {
    const int f32f = *flagp;
    const int i = blockIdx.x * 256 + threadIdx.x;
    if (i < n) dst[i] = f32f ? f2b(((const float*)src)[i]) : ((const u16*)src)[i];
}

// ---- dt_proj weights repacked planar: dst[l][jb][c][8] bf16, jb = dt-rank chunk (48 = 6*8) ----
__global__ void cvt_dtp(const void* __restrict__ src, u16* __restrict__ dst,
                        const int* __restrict__ flagp) {
    const int f32f = *flagp;
    const int i = blockIdx.x * 256 + threadIdx.x;
    if (i >= 2 * 6 * DI * 8) return;
    const int j = i & 7;
    const int c = (i >> 3) % DI;
    const int jb = ((i >> 3) / DI) % 6;
    const int l = i / (8 * DI * 6);
    dst[i] = f2b(ldin(src, ((size_t)(l * DI + c)) * DTR + jb * 8 + j, f32f));
}

// ---- precompute: conv weights [l][tap][c] f32, conv bias f32, nA = -exp(A_log) [l][n][c] ----
__global__ void prep_conv(const void* __restrict__ cw, const void* __restrict__ cb,
                          const void* __restrict__ A_log,
                          float* __restrict__ cwT, float* __restrict__ cbF,
                          float* __restrict__ nA, const int* __restrict__ flagp) {
    const int f32f = *flagp;
    const int i = blockIdx.x * 256 + threadIdx.x;
    if (i < 2 * 4 * DI) {
        const int l = i / (4 * DI), r = i - l * 4 * DI;
        const int tap = r / DI, c = r - tap * DI;
        cwT[i] = ldin(cw, (size_t)l * DI * 4 + (size_t)c * 4 + tap, f32f);
    }
    if (i < 2 * DI) cbF[i] = ldin(cb, i, f32f);
    if (i < 2 * 16 * DI) {
        const int l = i / (16 * DI), r = i - l * 16 * DI;
        const int n = r / DI, c = r - n * DI;
        nA[i] = -__expf(ldin(A_log, (size_t)l * DI * DS + (size_t)c * DS + n, f32f));
    }
}

// ---- check A[n] = (n+1)*A[0] structure (Mamba default init) ----
__global__ void chk_A(const float* __restrict__ nA, int* __restrict__ flagA) {
    int viol = 0;
    for (int i = threadIdx.x; i < 2 * 16 * DI; i += 256) {
        const int l = i / (16 * DI);
        const int rem = i - l * 16 * DI;
        const int n = rem / DI;
        const int c = rem - n * DI;
        const float a1 = nA[l * 16 * DI + c];
        const float want = (float)(n + 1) * a1;
        const float got = nA[i];
        if (fabsf(got - want) > 1e-4f * fabsf(want) + 1e-6f) viol = 1;
    }
    const float v = block_sum((float)viol);
    if (threadIdx.x == 0) *flagA = (v == 0.f) ? 1 : 0;
}

// ---- fused: embedding gather + rmsnorm(in_norm) -> h f32 AND rmsnorm(norm_w[0]) -> bf16 normed ----
__global__ void embed_rms2(const int* __restrict__ tokens, const void* __restrict__ embed,
                           const void* __restrict__ w_in, const void* __restrict__ w_l0,
                           float* __restrict__ h, u16* __restrict__ normed,
                           const int* __restrict__ flagp) {
    const int f32f = *flagp;
    const int f = blockIdx.x;
    const int tid = threadIdx.x;
    const int row = tokens[f];
    float v[3]; float ss = 0.f;
    #pragma unroll
    for (int i = 0; i < 3; ++i) {
        v[i] = ldin(embed, (size_t)row * DM + tid + 256 * i, f32f);
        ss += v[i] * v[i];
    }
    float tot = block_sum(ss);
    float rs = rsqrtf(tot * (1.f / DM) + EPSN);
    float ss2 = 0.f;
    #pragma unroll
    for (int i = 0; i < 3; ++i) {
        v[i] = v[i] * rs * ldin(w_in, tid + 256 * i, f32f);
        h[(size_t)f * DM + tid + 256 * i] = v[i];
        ss2 += v[i] * v[i];
    }
    tot = block_sum(ss2);
    rs = rsqrtf(tot * (1.f / DM) + EPSN);
    #pragma unroll
    for (int i = 0; i < 3; ++i)
        normed[(size_t)f * DM + tid + 256 * i] =
            f2b(v[i] * rs * ldin(w_l0, tid + 256 * i, f32f));
}

// ---- MFMA GEMM: C[M,N] = A[M,K](lda) * B[N,K](ldb)^T, bf16 in, f32 acc ----
// GEMM ledger (in_proj dispatch): 2-phase 57.8us | 3-buf counted-vmcnt 57.4us
// | +band-swizzle 63.9us (reverted) | BK=64 60.2us (reverted).
// Config: 3-buffer counted-vmcnt, linear block order, 48KB LDS (best measured).
// EPI: 0 = store bf16; 3 = f32 partial Pbuf[z][M][N]
template <int EPI, int TN_>
__global__ __launch_bounds__(256)
void gemm_bt(const u16* __restrict__ A, const u16* __restrict__ B,
             void* __restrict__ Cv, float* __restrict__ Pbuf,
             const int* __restrict__ flagp,
             int M, int N, int K, int lda, int ldb, int ldc, int ksplit) {
    constexpr int NJ = TN_ / 32;
    constexpr int LPS = (TN_ == 128) ? 4 : 3;   // loads per stage per thread
    __shared__ u16 sA[3][128 * 32];
    __shared__ u16 sB[3][TN_ * 32];
    const int tid = threadIdx.x;
    const int bm = blockIdx.x * 128;
    const int bn = blockIdx.y * TN_;
    const int lane = tid & 63, w = tid >> 6;
    const int wm = (w >> 1) * 64;
    const int wn = (w & 1) * (TN_ / 2);
    const int lr = lane & 15;
    const int q = lane >> 4;
    const int sw = (q ^ (lr & 3)) * 8;          // swizzled k-slot (u16 elems)

    int oA[4]; int oB[NJ];
    #pragma unroll
    for (int i = 0; i < 4; ++i) oA[i] = (wm + i * 16 + lr) * 32 + sw;
    #pragma unroll
    for (int j = 0; j < NJ; ++j) oB[j] = (wn + j * 16 + lr) * 32 + sw;

    const int r0 = tid >> 2;
    const int kp = ((tid & 3) ^ (r0 & 3)) * 8;  // global k offset (elems)

    const u16* gA0 = A + (size_t)(bm + r0) * lda + kp;
    const u16* gA1 = A + (size_t)(bm + r0 + 64) * lda + kp;
    const u16* gB0 = B + (size_t)(bn + r0) * ldb + kp;
    const u16* gB1 = (TN_ == 128) ? (B + (size_t)(bn + r0 + 64) * ldb + kp) : nullptr;

    f32x4 acc[4][NJ];
    #pragma unroll
    for (int i = 0; i < 4; ++i)
        #pragma unroll
        for (int j = 0; j < NJ; ++j)
            acc[i][j] = (f32x4){0.f, 0.f, 0.f, 0.f};

    const int kb = blockIdx.z * ksplit;
    const int ke = (kb + ksplit < K) ? (kb + ksplit) : K;
    const int nt = (ke - kb) >> 5;              // K tiles (K multiple of 32)

    auto stage = [&](int b, int t) {
        const int k0 = kb + t * 32;
        gld16(gA0 + k0, &sA[b][tid * 8]);
        gld16(gA1 + k0, &sA[b][(256 + tid) * 8]);
        gld16(gB0 + k0, &sB[b][tid * 8]);
        if constexpr (TN_ == 128) gld16(gB1 + k0, &sB[b][(256 + tid) * 8]);
    };

    // prologue: 2 tiles in flight; wait only for tile 0
    stage(0, 0);
    if (nt > 1) { stage(1, 1); waitbar<LPS>(); }
    else        { waitbar<0>(); }

    int cur = 0;
    for (int t = 0; t < nt; ++t) {
        short8_t af[4], bfr[NJ];
        #pragma unroll
        for (int i = 0; i < 4; ++i) af[i] = *(const short8_t*)&sA[cur][oA[i]];
        #pragma unroll
        for (int j = 0; j < NJ; ++j) bfr[j] = *(const short8_t*)&sB[cur][oB[j]];
        __builtin_amdgcn_sched_barrier(0);      // ds_reads stay before the stage

        if (t + 2 < nt) {
            int b2 = cur + 2; if (b2 >= 3) b2 -= 3;
            stage(b2, t + 2);
        }

        #pragma unroll
        for (int i = 0; i < 4; ++i)
            #pragma unroll
            for (int j = 0; j < NJ; ++j)
                acc[i][j] = __builtin_amdgcn_mfma_f32_16x16x32_bf16(af[i], bfr[j], acc[i][j], 0, 0, 0);

        if (t + 1 < nt) {
            if (t + 2 < nt) waitbar<LPS>();     // leave tile t+2 in flight
            else            waitbar<0>();       // last prefetch: drain
        }
        cur = (cur == 2) ? 0 : cur + 1;
    }

    // epilogue: C/D layout col=lane&15, row=(lane>>4)*4 + reg   [verified m89/m91]
    const int cr = (lane >> 4) * 4;
    const int cc = lane & 15;
    #pragma unroll
    for (int i = 0; i < 4; ++i) {
        const int gm0 = bm + wm + i * 16 + cr;
        #pragma unroll
        for (int j = 0; j < NJ; ++j) {
            const int gn = bn + wn + j * 16 + cc;
            if (gn < N) {
                #pragma unroll
                for (int r = 0; r < 4; ++r) {
                    float v = acc[i][j][r];
                    const size_t idx = (size_t)(gm0 + r) * ldc + gn;
                    if (EPI == 0) {
                        ((u16*)Cv)[idx] = f2b(v);
                    } else {
                        Pbuf[(size_t)blockIdx.z * M * N + idx] = v;
                    }
                }
            }
        }
    }
}

// ---- fused: reduce NSPL x_proj split-K partials -> bf16 dbl [MPAD,80]
//      AND dt_proj(rank-48) + softplus -> dtb [MPAD,1536].
__global__ __launch_bounds__(256)
void reduce_xp_dt(u16* __restrict__ dbl, u16* __restrict__ dtb,
                  const float* __restrict__ P, const u16* __restrict__ wdt,
                  const void* __restrict__ bias, int bias_off,
                  const int* __restrict__ flagp) {
    __shared__ float sdt[8 * DTR];              // [tok][48] f32
    const int f32f = *flagp;
    const int tid = threadIdx.x;
    const int g0 = blockIdx.x * 8;              // first token row of this block

    #pragma unroll
    for (int it = 0; it < 3; ++it) {
        const int idx = tid + it * 256;
        if (idx < 8 * DXP) {
            const size_t base = (size_t)g0 * DXP + idx;
            float s = 0.f;
            #pragma unroll
            for (int z = 0; z < NSPL; ++z) s += P[(size_t)z * MPAD * DXP + base];
            dbl[base] = f2b(s);
            const int tok = idx / DXP, col = idx - tok * DXP;
            if (col < DTR) sdt[tok * DTR + col] = s;
        }
    }
    __syncthreads();

    #pragma unroll 1
    for (int p = 0; p < 2; ++p) {
        float acc[3][8];
        #pragma unroll
        for (int kc = 0; kc < 3; ++kc)
            #pragma unroll
            for (int t = 0; t < 8; ++t) acc[kc][t] = 0.f;

        #pragma unroll 1
        for (int jb = 0; jb < 6; ++jb) {        // 6 chunks of 8 dt-rank dims
            float w[3][8];
            #pragma unroll
            for (int kc = 0; kc < 3; ++kc) {
                const int c = tid + (p * 3 + kc) * 256;
                const uint4 wv = *(const uint4*)(wdt + ((size_t)jb * DI + c) * 8);
                unp8(wv, w[kc]);
            }
            #pragma unroll
            for (int t = 0; t < 8; ++t) {
                float sj[8];
                *(float4*)&sj[0] = *(const float4*)&sdt[t * DTR + jb * 8];
                *(float4*)&sj[4] = *(const float4*)&sdt[t * DTR + jb * 8 + 4];
                #pragma unroll
                for (int kc = 0; kc < 3; ++kc)
                    #pragma unroll
                    for (int j = 0; j < 8; ++j)
                        acc[kc][t] += w[kc][j] * sj[j];
            }
        }

        #pragma unroll
        for (int kc = 0; kc < 3; ++kc) {
            const int c = tid + (p * 3 + kc) * 256;
            const float bv = ldin(bias, (size_t)(bias_off + c), f32f);
            #pragma unroll
            for (int t = 0; t < 8; ++t) {
                float v = acc[kc][t] + bv;
                v = (v > 20.f) ? v : __logf(1.f + __expf(v));
                dtb[(size_t)(g0 + t) * DI + c] = f2b(v);
            }
        }
    }
}

// ---- fused: h += out_proj partial (single slab) AND rmsnorm -> bf16 normed ----
__global__ void reduce_out_rms(float* __restrict__ h, const float* __restrict__ P,
                               const void* __restrict__ w, int woff,
                               u16* __restrict__ out, const int* __restrict__ flagp) {
    const int f32f = *flagp;
    const int f = blockIdx.x;
    const int tid = threadIdx.x;
    float v[3]; float ss = 0.f;
    #pragma unroll
    for (int i = 0; i < 3; ++i) {
        const size_t idx = (size_t)f * DM + tid + 256 * i;
        const float a = h[idx] + P[idx];
        h[idx] = a; v[i] = a; ss += a * a;
    }
    const float tot = block_sum(ss);
    const float rs = rsqrtf(tot * (1.f / DM) + EPSN);
    #pragma unroll
    for (int i = 0; i < 3; ++i)
        out[(size_t)f * DM + tid + 256 * i] =
            f2b(v[i] * rs * ldin(w, woff + tid + 256 * i, f32f));
}

// ---- fused: h += partial AND double rmsnorm -> d_out (end fusion) ----
__global__ void reduce_out_final(const float* __restrict__ h, const float* __restrict__ P,
                                 const void* __restrict__ wf, const void* __restrict__ wo,
                                 void* __restrict__ out, const int* __restrict__ flagp) {
    const int f32f = *flagp;
    const int f = blockIdx.x;
    const int tid = threadIdx.x;
    float v[3]; float ss = 0.f;
    #pragma unroll
    for (int i = 0; i < 3; ++i) {
        const size_t idx = (size_t)f * DM + tid + 256 * i;
        v[i] = h[idx] + P[idx];
        ss += v[i] * v[i];
    }
    float tot = block_sum(ss);
    float rs = rsqrtf(tot * (1.f / DM) + EPSN);
    float ss2 = 0.f;
    #pragma unroll
    for (int i = 0; i < 3; ++i) {
        v[i] = v[i] * rs * ldin(wf, tid + 256 * i, f32f);
        ss2 += v[i] * v[i];
    }
    tot = block_sum(ss2);
    rs = rsqrtf(tot * (1.f / DM) + EPSN);
    #pragma unroll
    for (int i = 0; i < 3; ++i) {
        const float r = v[i] * rs * ldin(wo, tid + 256 * i, f32f);
        const size_t idx = (size_t)f * DM + tid + 256 * i;
        if (f32f) ((float*)out)[idx] = r;
        else      ((u16*)out)[idx] = f2b(r);
    }
}

// ---- causal depthwise conv(K=4) + bias + silu; fully coalesced ----
__global__ void conv_silu(const u16* __restrict__ xz, const float* __restrict__ cwT,
                          const float* __restrict__ cbF, u16* __restrict__ xc) {
    const int gid = blockIdx.x * 256 + threadIdx.x;
    if (gid >= TOTAL * (DI / 2)) return;
    const int f = gid / (DI / 2);
    const int c = (gid - f * (DI / 2)) * 2;
    int s = 0;
    while (f >= d_OFF[s + 1]) s++;
    const int t = f - d_OFF[s];

    float2 acc = *(const float2*)(cbF + c);
    #pragma unroll
    for (int j = 0; j < 4; ++j) {
        if (t - 3 + j >= 0) {
            const u32 xp = *(const u32*)(xz + (size_t)(f - 3 + j) * (2 * DI) + c);
            const float2 wv = *(const float2*)(cwT + j * DI + c);
            acc.x += __uint_as_float(xp << 16) * wv.x;
            acc.y += __uint_as_float(xp & 0xFFFF0000u) * wv.y;
        }
    }
    const float s0 = acc.x / (1.f + __expf(-acc.x));
    const float s1 = acc.y / (1.f + __expf(-acc.y));
    *(u32*)(xc + (size_t)f * DI + c) = (u32)f2b(s0) | ((u32)f2b(s1) << 16);
}

// ==================== chunk-parallel selective scan (3 passes) ====================
__global__ __launch_bounds__(256)
void scan_part1(const u16* __restrict__ xcb, const u16* __restrict__ dtb,
                const u16* __restrict__ dbl,
                const float* __restrict__ nA, int aoff,
                float* __restrict__ Pb, float* __restrict__ Sb,
                const int* __restrict__ flagA) {
    __shared__ float sB[CH * 16];
    const int ch = blockIdx.x;
    const int g0 = ch * CH;
    const int tid = threadIdx.x;
    if (tid < CH * 2) {
        const int t = tid >> 1, half = (tid & 1) * 8;
        uint4 qv = *(const uint4*)(dbl + (size_t)(g0 + t) * DXP + DTR + half);
        float tmp[8]; unp8(qv, tmp);
        *(float4*)&sB[t * 16 + half]     = *(float4*)&tmp[0];
        *(float4*)&sB[t * 16 + half + 4] = *(float4*)&tmp[4];
    }
    __syncthreads();
    const int lane = tid & 63, w = tid >> 6;   // w = state quad (0..3)
    const int c = blockIdx.y * 64 + lane;      // 64 channels per block
    const int n0 = w * 4;
    const int fa = *flagA;

    float A[4];
    #pragma unroll
    for (int k = 0; k < 4; ++k) A[k] = nA[aoff + (n0 + k) * DI + c];
    const float a1 = nA[aoff + c];             // state-0 A for this channel
    float h[4] = {0.f, 0.f, 0.f, 0.f};
    float sdt = 0.f;

    u16 xu = xcb[(size_t)g0 * DI + c];
    u16 du = dtb[(size_t)g0 * DI + c];

    auto body = [&](auto tag) {
        constexpr bool FA = decltype(tag)::value;
        for (int t = 0; t < CH; ++t) {
            const float x = b2f(xu), dtv = b2f(du);
            if (t + 1 < CH) {
                xu = xcb[(size_t)(g0 + t + 1) * DI + c];
                du = dtb[(size_t)(g0 + t + 1) * DI + c];
            }
            const float4 Bv = *(const float4*)&sB[t * 16 + n0];   // broadcast
            const float dtx = dtv * x;
            sdt += dtv;
            float dA[4];
            if constexpr (FA) {
                const float e1 = __expf(dtv * a1);
                const float e2 = e1 * e1, e4 = e2 * e2, e8 = e4 * e4;
                const float base = (w == 0) ? 1.f : (w == 1) ? e4 : (w == 2) ? e8 : e8 * e4;
                dA[0] = base * e1; dA[1] = dA[0] * e1;
                dA[2] = dA[1] * e1; dA[3] = dA[2] * e1;
            } else {
                #pragma unroll
                for (int k = 0; k < 4; ++k) dA[k] = __expf(dtv * A[k]);
            }
            const float bw[4] = {Bv.x, Bv.y, Bv.z, Bv.w};
            #pragma unroll
            for (int k = 0; k < 4; ++k)
                h[k] = dA[k] * h[k] + dtx * bw[k];
        }
    };
    if (fa) body(BTrue{}); else body(BFalse{});

    #pragma unroll
    for (int k = 0; k < 4; ++k) {
        const size_t idx = ((size_t)ch * 16 + n0 + k) * DI + c;
        Pb[idx] = __expf(A[k] * sdt);          // prod_t exp(A dt_t) = exp(A*sum)
        Sb[idx] = h[k];
    }
}

__global__ __launch_bounds__(256)
void scan_part2(const float* __restrict__ Pb, const float* __restrict__ Sb,
                float* __restrict__ Hin) {
    const int s = blockIdx.x;                         // subject
    const int qd = blockIdx.y * 256 + threadIdx.x;    // n*DI + c  (< 16*DI)
    const int j0 = d_OFF[s] / CH;
    const int cnt = (d_OFF[s + 1] - d_OFF[s]) / CH;
    float h = 0.f;
    for (int j = 0; j < cnt; ++j) {
        const size_t idx = (size_t)(j0 + j) * (16 * DI) + qd;
        const float p = Pb[idx], sv = Sb[idx];
        Hin[idx] = h;
        h = p * h + sv;
    }
}

__global__ __launch_bounds__(256)
void scan_part3(const u16* __restrict__ xcb, const u16* __restrict__ dtb,
                const u16* __restrict__ xz, const u16* __restrict__ dbl,
                const float* __restrict__ nA, int aoff,
                const void* __restrict__ Dp, int doff,
                const float* __restrict__ Hin, u16* __restrict__ yb,
                const int* __restrict__ flagA, const int* __restrict__ flagp) {
    __shared__ float sBC[CH * 32];
    const int f32f = *flagp;
    const int ch = blockIdx.x;
    const int g0 = ch * CH;
    const int tid = threadIdx.x;
    if (tid < CH * 4) {
        const int t = tid >> 2, r = (tid & 3) * 8;
        uint4 qv = *(const uint4*)(dbl + (size_t)(g0 + t) * DXP + DTR + r);
        float tmp[8]; unp8(qv, tmp);
        *(float4*)&sBC[t * 32 + r]     = *(float4*)&tmp[0];
        *(float4*)&sBC[t * 32 + r + 4] = *(float4*)&tmp[4];
    }
    __syncthreads();
    const int lane = tid & 63, w = tid >> 6;
    const int c = (blockIdx.y * 4 + w) * 64 + lane;   // 256 channels/block
    const int fa = *flagA;

    float A[16];
    #pragma unroll
    for (int n = 0; n < 16; ++n) A[n] = nA[aoff + n * DI + c];
    const float a1 = A[0];
    const float Dv = ldin(Dp, (size_t)doff + c, f32f);
    float h[16];
    #pragma unroll
    for (int n = 0; n < 16; ++n) h[n] = Hin[((size_t)ch * 16 + n) * DI + c];

    u16 xu = xcb[(size_t)g0 * DI + c];
    u16 du = dtb[(size_t)g0 * DI + c];
    u16 zu = xz[(size_t)g0 * (2 * DI) + DI + c];

    auto body = [&](auto tag) {
        constexpr bool FA = decltype(tag)::value;
        for (int t = 0; t < CH; ++t) {
            const float x = b2f(xu), dtv = b2f(du), z = b2f(zu);
            if (t + 1 < CH) {
                xu = xcb[(size_t)(g0 + t + 1) * DI + c];
                du = dtb[(size_t)(g0 + t + 1) * DI + c];
                zu = xz[(size_t)(g0 + t + 1) * (2 * DI) + DI + c];
            }
            float Bv[16], Cvv[16];
            *(float4*)&Bv[0]   = *(const float4*)&sBC[t * 32 + 0];
            *(float4*)&Bv[4]   = *(const float4*)&sBC[t * 32 + 4];
            *(float4*)&Bv[8]   = *(const float4*)&sBC[t * 32 + 8];
            *(float4*)&Bv[12]  = *(const float4*)&sBC[t * 32 + 12];
            *(float4*)&Cvv[0]  = *(const float4*)&sBC[t * 32 + 16];
            *(float4*)&Cvv[4]  = *(const float4*)&sBC[t * 32 + 20];
            *(float4*)&Cvv[8]  = *(const float4*)&sBC[t * 32 + 24];
            *(float4*)&Cvv[12] = *(const float4*)&sBC[t * 32 + 28];
            const float dtx = dtv * x;
            float acc = 0.f;
            if constexpr (FA) {
                const float e1 = __expf(dtv * a1);
                float ep[17];
                ep[1] = e1;
                #pragma unroll
                for (int k = 2; k <= 16; ++k) ep[k] = ep[k >> 1] * ep[k - (k >> 1)];
                #pragma unroll
                for (int n = 0; n < 16; ++n) {
                    h[n] = ep[n + 1] * h[n] + dtx * Bv[n];
                    acc += h[n] * Cvv[n];
                }
            } else {
                #pragma unroll
                for (int n = 0; n < 16; ++n) {
                    const float dA = __expf(dtv * A[n]);
                    h[n] = dA * h[n] + dtx * Bv[n];
                    acc += h[n] * Cvv[n];
                }
            }
            const float sig = 1.f / (1.f + __expf(-z));
            yb[(size_t)(g0 + t) * DI + c] = f2b((acc + x * Dv) * (z * sig));
        }
    };
    if (fa) body(BTrue{}); else body(BFalse{});
}

extern "C" void kernel_launch(void* const* d_in, const int* in_sizes, int n_in,
                              void* d_out, int out_size, void* d_ws, size_t ws_size,
                              hipStream_t stream) {
    const int*  tokens     = (const int*)d_in[0];
    const void* embed      = d_in[1];
    const void* in_norm_w  = d_in[2];
    const void* out_norm_w = d_in[3];
    const void* norm_w     = d_in[4];
    const void* in_proj_w  = d_in[5];
    const void* conv_w     = d_in[6];
    const void* conv_b     = d_in[7];
    const void* x_proj_w   = d_in[8];
    const void* dt_proj_w  = d_in[9];
    const void* dt_proj_b  = d_in[10];
    const void* A_log      = d_in[11];
    const void* D_param    = d_in[12];
    const void* out_proj_w = d_in[13];
    const void* norm_f_w   = d_in[14];

    char* ws = (char*)d_ws;
    float* h    = (float*)(ws);                     // MPAD*768*4  = 21,233,664
    u16* normed = (u16*)(ws + 21233664);            // MPAD*768*2 = 10,616,832 region
    u16* xz     = (u16*)(ws + 31850496);            // MPAD*3072*2 (out_proj partial alias)
    u16* xcb    = (u16*)(ws + 74317824);            // MPAD*1536*2
    u16* dbl    = (u16*)(ws + 95551488);            // MPAD*80*2
    u16* dtb    = (u16*)(ws + 96657408);            // MPAD*1536*2
    u16* yb     = (u16*)(ws + 117891072);           // MPAD*1536*2 (aliases: Sb, x_proj partials)
    u16* w_ip   = (u16*)(ws + 139124736);           // 2*3072*768  bf16
    u16* w_op   = (u16*)(ws + 148561920);           // 2*768*1536  bf16
    u16* w_xp   = (u16*)(ws + 153280512);           // 2*80*1536   bf16
    u16* w_dtp  = (u16*)(ws + 153772032);           // 2*6*1536*8  bf16 planar [l][jb][c][8]
    int* flag   = (int*)(ws + 154165248);
    int* flagA  = (int*)(ws + 154165252);
    float* cwT  = (float*)(ws + 154165504);         // 2*4*1536 f32
    float* cbF  = (float*)(ws + 154214656);         // 2*1536 f32
    float* nA   = (float*)(ws + 154226944);         // 2*16*1536 f32 -> end 154,423,552
    // Pb/Hin live in the normed region: NCH*16*DI*4 = 10,518,528 <= 10,616,832 (CH=64 only!)
    float* Pb  = (float*)normed;   // scan pass1 out / pass2 in; Hin overwrites in pass2
    float* Sb  = (float*)yb;       // scan pass1 out / pass2 in (region = 21,233,664 B)
    float* Hin = (float*)normed;
    float* Pxp = (float*)yb;       // x_proj split-K partials: NSPL*MPAD*80*4 = 8,847,360 OK
    float* Pop = (float*)xz;       // out_proj partial (single slab, 21.2 MB)

    detect_dtype<<<1, 64, 0, stream>>>((const u16*)embed, flag);

    cvt_any<<<(2 * 2 * DI * DM + 255) / 256, 256, 0, stream>>>(in_proj_w,  w_ip, 2 * 2 * DI * DM, flag);
    cvt_any<<<(2 * DM * DI + 255) / 256, 256, 0, stream>>>(out_proj_w, w_op, 2 * DM * DI, flag);
    cvt_any<<<(2 * DXP * DI + 255) / 256, 256, 0, stream>>>(x_proj_w,  w_xp, 2 * DXP * DI, flag);
    cvt_dtp<<<(2 * 6 * DI * 8 + 255) / 256, 256, 0, stream>>>(dt_proj_w, w_dtp, flag);
    prep_conv<<<(2 * 16 * DI + 255) / 256, 256, 0, stream>>>(conv_w, conv_b, A_log, cwT, cbF, nA, flag);
    chk_A<<<1, 256, 0, stream>>>(nA, flagA);

    embed_rms2<<<TOTAL, 256, 0, stream>>>(tokens, embed, in_norm_w, norm_w, h, normed, flag);

    for (int l = 0; l < 2; ++l) {
        // in_proj: [MPAD,768] x [3072,768]^T -> xz
        gemm_bt<0, 128><<<dim3(MPAD / 128, 3072 / 128, 1), 256, 0, stream>>>(
            normed, w_ip + (size_t)l * 2 * DI * DM, xz, nullptr, flag,
            MPAD, 2 * DI, DM, DM, DM, 2 * DI, DM);
        conv_silu<<<(TOTAL * (DI / 2) + 255) / 256, 256, 0, stream>>>(
            xz, cwT + (size_t)l * 4 * DI, cbF + (size_t)l * DI, xcb);
        // x_proj: [MPAD,1536] x [80,1536]^T, split-K 4 (12 K-tiles each)
        gemm_bt<3, 64><<<dim3(MPAD / 128, 2, NSPL), 256, 0, stream>>>(
            xcb, w_xp + (size_t)l * DXP * DI, nullptr, Pxp, flag,
            MPAD, DXP, DI, DI, DI, DXP, DI / NSPL);
        // fused: partial-reduce -> dbl  +  dt_proj(rank-48) + softplus -> dtb
        reduce_xp_dt<<<MPAD / 8, 256, 0, stream>>>(
            dbl, dtb, Pxp, w_dtp + (size_t)l * 6 * DI * 8, dt_proj_b, l * DI, flag);
        // chunk-parallel selective scan (CH=64)
        scan_part1<<<dim3(NCH, DI / 64), 256, 0, stream>>>(
            xcb, dtb, dbl, nA, l * 16 * DI, Pb, Sb, flagA);
        scan_part2<<<dim3(NSUBJ, 16 * DI / 256), 256, 0, stream>>>(Pb, Sb, Hin);
        scan_part3<<<dim3(NCH, 6), 256, 0, stream>>>(
            xcb, dtb, xz, dbl, nA, l * 16 * DI, D_param, l * DI, Hin, yb, flagA, flag);
        // out_proj: [MPAD,1536] x [768,1536]^T, TN=128 (2x B-reuse per staged byte)
        gemm_bt<3, 128><<<dim3(MPAD / 128, DM / 128, 1), 256, 0, stream>>>(
            yb, w_op + (size_t)l * DM * DI, nullptr, Pop, flag,
            MPAD, DM, DI, DI, DI, DM, DI);
        // fused residual-add + norm (layer boundary / final)
        if (l == 0)
            reduce_out_rms<<<TOTAL, 256, 0, stream>>>(h, Pop, norm_w, DM, normed, flag);
        else
            reduce_out_final<<<TOTAL, 256, 0, stream>>>(h, Pop, norm_f_w, out_norm_w, d_out, flag);
    }
}